// Round 1
// baseline (2567.310 us; speedup 1.0000x reference)
//
#include <hip/hip_runtime.h>
#include <math.h>

#define BRR 512
#define LLL 64
#define KKK 16
#define EEE 64
#define CC2 8
#define PPP 1024
#define BN_EPS 1e-5f
#define NSTRIPE 16

__device__ __forceinline__ float relu_f(float v){ return v>0.f?v:0.f; }
// Row-padded W1 layout: stride 68 + 4-float stagger per 8-row octet.
// Monotone (no overlap: gaps 68/72; max 63*68+28+63=4375<4384) and the wave's
// 8 og-rows (r=og*8+j) land on distinct 4-bank groups (offset 4*og mod 32).
__device__ __forceinline__ int lds_row(int r){ return r*68 + (((r>>3)&7)<<2); }

// ---- d_ws float layout ----
#define OFF_HBL  0u          // [(b*64+l)*8+c2]            262144
#define OFF_HBK  262144u     // [(b*16+k)*8+c2]             65536
#define OFF_Y0   327680u     // [b*1024 + k*64+c]          524288
#define OFF_X1   851968u     // [(b*64+l)*64+c] M0L->X1   2097152
#define OFF_Y1   2949120u    // [b*1024 + k*64+o] M0K->Y1  524288
#define OFF_X2   3473408u    // [(b*64+l)*8+o2]            262144
#define OFF_Y2   3735552u    // [(b*16+k)*8+o2]             65536
#define OFF_M1L  3801088u    // [b*4096 + l*64+c] raw k-mean of T1   2097152
#define OFF_M1K  5898240u    // [b*1024 + k*64+c] raw l-mean (atomic) 524288
#define OFF_SUM0 6422528u
#define OFF_SSQ0 6423552u
#define OFF_SUM1 6424576u
#define OFF_SSQ1 6425600u
#define OFF_S0   6426624u
#define OFF_T0   6426688u
#define OFF_S1   6426752u
#define OFF_T1   6426816u
#define WS_FLOATS 6426880u   // 25,707,520 bytes

// ---------------------------------------------------------------------------
// K0: zero atomic regions (M1K + 4 stat arrays, contiguous 528384 floats).
__global__ void k_zero(float4* __restrict__ p, int n4){
  int t = blockIdx.x*256 + threadIdx.x;
  if (t < n4) p[t] = make_float4(0.f,0.f,0.f,0.f);
}

// K1: per-b prep. HbL,HbK,y0,M0K,M0L + BN0 channel sums. All inputs f32.
__global__ __launch_bounds__(256) void k_prep(const float* __restrict__ Hr,
                                              const float* __restrict__ Hi,
                                              const float* __restrict__ P40,
                                              float* __restrict__ ws){
  __shared__ float sm[9344];
  int b = blockIdx.x, tid = threadIdx.x;
  const float* hrg = Hr + (size_t)b*4096;
  const float* hig = Hi + (size_t)b*4096;
  for (int t=tid;t<4096;t+=256){ sm[t]=hrg[t]; sm[4096+t]=hig[t]; }
  for (int t=tid;t<512;t+=256){ int c=t&63,j=t>>6; sm[8192+j*64+c]=P40[c*8+j]; }
  __syncthreads();
  for (int t=tid;t<512;t+=256){ int l=t>>3,c2=t&7;          // HbL [8704,9216)
    const float* src=sm+((c2<4)?0:4096); int u=c2&3;
    float s=0.f;
    #pragma unroll
    for(int k=0;k<16;++k) s+=src[(l*16+k)*4+u];
    sm[8704+t]=s*(1.f/16.f); }
  for (int t=tid;t<128;t+=256){ int k=t>>3,c2=t&7;          // HbK [9216,9344)
    const float* src=sm+((c2<4)?0:4096); int u=c2&3;
    float s=0.f;
    for(int l=0;l<64;++l) s+=src[(l*16+k)*4+u];
    sm[9216+t]=s*(1.f/64.f); }
  __syncthreads();
  for (int t=tid;t<1024;t+=256){ int k=t>>6,c=t&63; float s=0.f;   // y0 [4096,5120)
    #pragma unroll
    for(int j=0;j<8;++j) s+=sm[8192+j*64+c]*sm[9216+k*8+j];
    sm[4096+t]=0.1f*s; }
  for (int t=tid;t<4096;t+=256){ int l=t>>6,c=t&63; float s=0.f;   // x0 [0,4096)
    #pragma unroll
    for(int j=0;j<8;++j) s+=sm[8192+j*64+c]*sm[8704+l*8+j];
    sm[t]=0.1f*s; }
  __syncthreads();
  for (int t=tid;t<1024;t+=256){ int c=t&63; float yv=sm[4096+t]; float s=0.f;  // M0K [5120,6144)
    for(int l=0;l<64;++l) s+=relu_f(sm[l*64+c]+yv);
    sm[5120+t]=s*(1.f/64.f); }
  float ssum=0.f, ssq=0.f;                       // channel c = tid&63 (stride 256 preserves it)
  for (int t=tid;t<4096;t+=256){ int c=t&63; float xv=sm[t]; float s=0.f;
    #pragma unroll
    for(int k=0;k<16;++k){ float v=relu_f(xv+sm[4096+k*64+c]); s+=v; ssq+=v*v; }
    ssum+=s;
    ws[OFF_X1+(size_t)b*4096+t]=s*(1.f/16.f); }  // M0L
  __syncthreads();
  sm[6144+tid]=ssum; sm[6400+tid]=ssq;
  __syncthreads();
  if (tid<64){
    float ts =sm[6144+tid]+sm[6208+tid]+sm[6272+tid]+sm[6336+tid];
    float tss=sm[6400+tid]+sm[6464+tid]+sm[6528+tid]+sm[6592+tid];
    int stripe = b & (NSTRIPE-1);
    atomicAdd(&ws[OFF_SUM0+stripe*64+tid], ts);
    atomicAdd(&ws[OFF_SSQ0+stripe*64+tid], tss);
  }
  for (int t=tid;t<512;t+=256)  ws[OFF_HBL+(size_t)b*512+t]=sm[8704+t];
  for (int t=tid;t<128;t+=256)  ws[OFF_HBK+(size_t)b*128+t]=sm[9216+t];
  for (int t=tid;t<1024;t+=256) ws[OFF_Y0+(size_t)b*1024+t]=sm[4096+t];
  for (int t=tid;t<1024;t+=256) ws[OFF_Y1+(size_t)b*1024+t]=sm[5120+t];   // M0K
}

// K2: finalize BN -> s,t.
__global__ void k_bn(float* __restrict__ ws, const float* __restrict__ g_,
                     const float* __restrict__ b_, unsigned sumOff, unsigned outOff){
  int tid = threadIdx.x;
  if (tid < 64){
    float s=0.f, ss=0.f;
    for (int i=0;i<NSTRIPE;++i){ s+=ws[sumOff+i*64+tid]; ss+=ws[sumOff+1024+i*64+tid]; }
    const float invN = 1.0f/((float)BRR*LLL*KKK);
    float mu=s*invN, var=ss*invN-mu*mu;
    float sc = g_[tid]/sqrtf(var+BN_EPS);
    ws[outOff+tid]=sc;
    ws[outOff+64+tid]=b_[tid]-mu*sc;
  }
}

// K3: X1/Y1 in place over M0L/M0K.
__global__ __launch_bounds__(256) void k_xy1(float* __restrict__ ws,
                                             const float* __restrict__ P21,
                                             const float* __restrict__ P41){
  __shared__ float wt[4096], p41[512], mrow[1024], hbs[128], s0l[64], t0l[64];
  int bx = blockIdx.x, tid = threadIdx.x;
  for (int t=tid;t<4096;t+=256) wt[t] = 2.0f*P21[(t&63)*64 + (t>>6)];  // [c*64+o]
  for (int t=tid;t<512;t+=256)  p41[t] = P41[t];                        // [o*8+j]
  if (tid<64){ s0l[tid]=ws[OFF_S0+tid]; t0l[tid]=ws[OFF_T0+tid]; }
  bool isX = bx < 2048;
  int row0 = isX ? bx*16 : (bx-2048)*16;
  if (isX){
    for (int t=tid;t<1024;t+=256) mrow[t] = ws[OFF_X1+(size_t)row0*64+t];
    if (tid<128) hbs[tid] = ws[OFF_HBL+(size_t)row0*8+tid];
  } else {
    for (int t=tid;t<1024;t+=256) mrow[t] = ws[OFF_Y1+(size_t)row0*64+t];
    if (tid<128) hbs[tid] = ws[OFF_HBK+(size_t)row0*8+tid];
  }
  __syncthreads();
  for (int t=tid;t<1024;t+=256){ int c=t&63; mrow[t]=s0l[c]*mrow[t]+t0l[c]; }
  __syncthreads();
  int r4 = tid>>6, o = tid&63;
  #pragma unroll
  for (int rr=0;rr<4;++rr){
    int rl = rr*4 + r4;
    float s=0.f;
    for (int c=0;c<64;++c) s += wt[c*64+o]*mrow[rl*64+c];
    float s2=0.f;
    #pragma unroll
    for (int j=0;j<8;++j) s2 += p41[o*8+j]*hbs[rl*8+j];
    float res = s + 0.1f*s2;
    if (isX) ws[OFF_X1+(size_t)(row0+rl)*64+o] = res;
    else     ws[OFF_Y1+(size_t)(row0+rl)*64+o] = res;
  }
}

// ---- T1 tile recompute. Thread (og,pg): channels c0=og*8..+7, l=pblk*8+lloc, k=(pg&3)*4+i.
#define T_W1   0
#define T_X08  4384
#define T_Y0   4896
#define T_X1   5984
#define T_Y1   6496
#define T_S0   7520
#define T_T0   7584
#define T_P4T0 7648
#define T_HB8  8160
#define T_END  8224

__device__ void t1_tile(float* sm, const float* __restrict__ ws,
                        const float* __restrict__ P11, const float* __restrict__ P40,
                        int b, int pblk, int tid,
                        float acc[8][4], int og, int pg, int lloc, int c0){
  for (int t=tid;t<4096;t+=256){ int o=t>>6,c=t&63; sm[T_W1+lds_row(o)+c]=2.0f*P11[t]; }
  for (int t=tid;t<1024;t+=256){ int k=t>>6,c=t&63; sm[T_Y0+k*68+c]=ws[OFF_Y0+(size_t)b*1024+t]; }
  for (int t=tid;t<512;t+=256)  sm[T_X1+t]=ws[OFF_X1+((size_t)b*64+pblk*8)*64+t];
  for (int t=tid;t<1024;t+=256) sm[T_Y1+t]=ws[OFF_Y1+(size_t)b*1024+t];
  for (int t=tid;t<512;t+=256){ int c=t&63,j=t>>6; sm[T_P4T0+j*64+c]=P40[c*8+j]; }
  if (tid<64){ sm[T_S0+tid]=ws[OFF_S0+tid]; sm[T_T0+tid]=ws[OFF_T0+tid]; }
  else if (tid<128){ int t2=tid-64; sm[T_HB8+t2]=ws[OFF_HBL+((size_t)b*64+pblk*8)*8+t2]; }
  __syncthreads();
  for (int e=tid;e<512;e+=256){ int l=e>>6,c=e&63; float s=0.f;
    #pragma unroll
    for(int j=0;j<8;++j) s += sm[T_P4T0+j*64+c]*sm[T_HB8+l*8+j];
    sm[T_X08+e]=0.1f*s; }
  __syncthreads();
  {
    float xb[8];
    *(float4*)&xb[0] = *(const float4*)&sm[T_X1 + lloc*64 + c0];
    *(float4*)&xb[4] = *(const float4*)&sm[T_X1 + lloc*64 + c0 + 4];
    #pragma unroll
    for (int i=0;i<4;++i){
      int k=(pg&3)*4+i;
      float yb[8];
      *(float4*)&yb[0] = *(const float4*)&sm[T_Y1 + k*64 + c0];
      *(float4*)&yb[4] = *(const float4*)&sm[T_Y1 + k*64 + c0 + 4];
      #pragma unroll
      for (int j=0;j<8;++j) acc[j][i]=xb[j]+yb[j];
    }
  }
  #pragma unroll
  for (int c4=0;c4<16;++c4){
    float4 xr  = *(const float4*)&sm[T_X08 + lloc*64 + c4*4];
    float4 s0v = *(const float4*)&sm[T_S0 + c4*4];
    float4 t0v = *(const float4*)&sm[T_T0 + c4*4];
    float4 aa[4];
    #pragma unroll
    for (int i=0;i<4;++i){
      int k=(pg&3)*4+i;
      float4 yr = *(const float4*)&sm[T_Y0 + k*68 + c4*4];
      aa[i].x = s0v.x*relu_f(xr.x+yr.x)+t0v.x;
      aa[i].y = s0v.y*relu_f(xr.y+yr.y)+t0v.y;
      aa[i].z = s0v.z*relu_f(xr.z+yr.z)+t0v.z;
      aa[i].w = s0v.w*relu_f(xr.w+yr.w)+t0v.w;
    }
    #pragma unroll
    for (int j=0;j<8;++j){
      float4 w = *(const float4*)&sm[T_W1 + lds_row(c0+j) + c4*4];
      #pragma unroll
      for (int i=0;i<4;++i)
        acc[j][i] += w.x*aa[i].x + w.y*aa[i].y + w.z*aa[i].z + w.w*aa[i].w;
    }
  }
  #pragma unroll
  for (int j=0;j<8;++j)
    #pragma unroll
    for (int i=0;i<4;++i) acc[j][i] = relu_f(acc[j][i]);
}

// K4: fused tile pass -> BN1 channel sums + raw M1L (k-mean) + raw M1K (l-mean).
// BN1 is affine per channel, so mean(s1*T1+t1) = s1*mean(T1)+t1: the raw means
// can be produced in the SAME pass as the stats, eliminating the old k_xy2
// t1_tile recompute (and its 32-way-conflict LDS overlay) entirely.
#define MK_OFF 8224   // 4 wave-partials, [16][68] each, XOR-swizzled: [8224,12576)
__global__ __launch_bounds__(256) void k_pass1(float* __restrict__ ws,
                                               const float* __restrict__ P11,
                                               const float* __restrict__ P40){
  __shared__ float sm[12576];   // stats reuse [8224,12448) after mk phase
  int bid=blockIdx.x, b=bid>>3, pblk=bid&7, tid=threadIdx.x;
  int og=tid&7, pg=tid>>3, lloc=pg>>2, kg=pg&3, c0=og*8;
  float acc[8][4];
  t1_tile(sm, ws, P11, P40, b, pblk, tid, acc, og, pg, lloc, c0);
  // ---- M1K partial: lloc-pair sum in-register (tid bit5 = lloc bit0), then
  //      4-wave LDS reduce. Write swizzle c^(kg<<3) spreads kg into the bank
  //      index (the old overlay ignored kg -> 32-way conflict).
  int wv = tid>>6;
  #pragma unroll
  for (int j=0;j<8;++j){
    #pragma unroll
    for (int i=0;i<4;++i){
      float v = acc[j][i] + __shfl_xor(acc[j][i], 32, 64);
      if ((tid & 32)==0)
        sm[MK_OFF + wv*1088 + (kg*4+i)*68 + ((og^kg)<<3) + j] = v;
    }
  }
  __syncthreads();
  for (int e=tid;e<1024;e+=256){           // k uniform per wave -> conflict-free reads
    int k=e>>6;
    int cs=(e&63) ^ (((k>>2)&3)<<3);
    int a = MK_OFF + k*68 + cs;
    float v = sm[a] + sm[a+1088] + sm[a+2176] + sm[a+3264];
    atomicAdd(&ws[OFF_M1K+(size_t)b*1024+e], v*(1.f/64.f));
  }
  // ---- per-channel sums for stats + M1L (k-sum via shfl over kg bits 3,4) ----
  float sj[8], qj[8];
  #pragma unroll
  for (int j=0;j<8;++j){
    sj[j]=acc[j][0]+acc[j][1]+acc[j][2]+acc[j][3];
    qj[j]=acc[j][0]*acc[j][0]+acc[j][1]*acc[j][1]+acc[j][2]*acc[j][2]+acc[j][3]*acc[j][3];
  }
  float rs[8];
  #pragma unroll
  for (int j=0;j<8;++j){
    float r=sj[j];
    r += __shfl_xor(r, 8, 64);
    r += __shfl_xor(r, 16, 64);
    rs[j]=r;
  }
  if (kg==0){
    const float inv16 = 1.f/16.f;
    float4 v0 = make_float4(rs[0]*inv16, rs[1]*inv16, rs[2]*inv16, rs[3]*inv16);
    float4 v1 = make_float4(rs[4]*inv16, rs[5]*inv16, rs[6]*inv16, rs[7]*inv16);
    size_t base = OFF_M1L + ((size_t)b*64 + pblk*8 + lloc)*64 + c0;
    *(float4*)&ws[base]   = v0;
    *(float4*)&ws[base+4] = v1;
  }
  __syncthreads();   // mk reads done -> reuse region for stats
  #pragma unroll
  for (int j=0;j<8;++j){
    sm[8224  + (c0+j)*33 + pg] = sj[j];
    sm[10336 + (c0+j)*33 + pg] = qj[j];
  }
  __syncthreads();
  if (tid<64){
    float ts=0.f, tss=0.f;
    for (int g=0; g<32; ++g){ ts += sm[8224+tid*33+g]; tss += sm[10336+tid*33+g]; }
    int stripe = b & (NSTRIPE-1);
    atomicAdd(&ws[OFF_SUM1+stripe*64+tid], ts);
    atomicAdd(&ws[OFF_SSQ1+stripe*64+tid], tss);
  }
}

// K5: tiny per-b pass: X2/Y2 from raw M1L/M1K + BN1 affine. Padded stride 68
// keeps every inner-loop LDS read conflict-free (8 distinct banks x 8-lane
// broadcast). No atomics (M1K is fully reduced).
__global__ __launch_bounds__(256) void k_xy2s(float* __restrict__ ws,
                                              const float* __restrict__ P22,
                                              const float* __restrict__ P42){
  __shared__ float mln[4352];   // [l][68] : s1*M1L+t1
  __shared__ float mkn[1088];   // [k][68] : s1*M1K+t1
  __shared__ float w2[512];     // [c*8+o2] = 2*P22[o2][c]
  __shared__ float p42s[64];    // [o2*8+j]
  __shared__ float hbl[512];    // [l*8+j]
  __shared__ float hbk[128];    // [k*8+j]
  __shared__ float s1l[64], t1l[64];
  int b = blockIdx.x, tid = threadIdx.x;
  if (tid<64){ s1l[tid]=ws[OFF_S1+tid]; t1l[tid]=ws[OFF_T1+tid]; }
  for (int t=tid;t<512;t+=256) w2[t] = 2.0f*P22[(t&7)*64 + (t>>3)];
  if (tid<64) p42s[tid] = P42[tid];
  for (int t=tid;t<512;t+=256) hbl[t] = ws[OFF_HBL+(size_t)b*512+t];
  if (tid<128) hbk[tid] = ws[OFF_HBK+(size_t)b*128+tid];
  __syncthreads();
  for (int t=tid;t<4096;t+=256){ int l=t>>6,c=t&63;
    mln[l*68+c] = s1l[c]*ws[OFF_M1L+(size_t)b*4096+t] + t1l[c]; }
  for (int t=tid;t<1024;t+=256){ int k=t>>6,c=t&63;
    mkn[k*68+c] = s1l[c]*ws[OFF_M1K+(size_t)b*1024+t] + t1l[c]; }
  __syncthreads();
  for (int t=tid;t<512;t+=256){
    int l=t>>3, o2=t&7;
    float s=0.f;
    for (int c=0;c<64;++c) s += w2[c*8+o2]*mln[l*68+c];
    float s2=0.f;
    #pragma unroll
    for (int j=0;j<8;++j) s2 += p42s[o2*8+j]*hbl[l*8+j];
    ws[OFF_X2+(size_t)b*512+t] = s + 0.1f*s2;
  }
  if (tid<128){
    int k=tid>>3, o2=tid&7;
    float s=0.f;
    for (int c=0;c<64;++c) s += w2[c*8+o2]*mkn[k*68+c];
    float s2=0.f;
    #pragma unroll
    for (int j=0;j<8;++j) s2 += p42s[o2*8+j]*hbk[k*8+j];
    ws[OFF_Y2+(size_t)b*128+tid] = s + 0.1f*s2;
  }
}

// K6: tile pass + layer-2 + normalize + output (unchanged).
__global__ __launch_bounds__(256) void k_final(const float* __restrict__ ws,
                                               const float* __restrict__ P11,
                                               const float* __restrict__ P40,
                                               const float* __restrict__ P12,
                                               float* __restrict__ out,
                                               long long out_cap, int interleaved){
  __shared__ float sm[9152];   // T1c [0,8512); W2l [8512,9024); s1 [9024); t1 [9088)
  int bid=blockIdx.x, b=bid>>3, pblk=bid&7, tid=threadIdx.x;
  int og=tid&7, pg=tid>>3, lloc=pg>>2, c0=og*8;
  for (int t=tid;t<512;t+=256) sm[8512+t] = 2.0f*P12[t];   // [o2*64+c]
  if (tid<64) sm[9024+tid]=ws[OFF_S1+tid];
  else if (tid<128) sm[9088+(tid-64)]=ws[OFF_T1+(tid-64)];
  float acc[8][4];
  t1_tile(sm, ws, P11, P40, b, pblk, tid, acc, og, pg, lloc, c0);
  __syncthreads();
  {
    int kg = pg&3;
    #pragma unroll
    for (int i=0;i<4;++i){
      int p = lloc*16 + kg*4 + i;
      #pragma unroll
      for (int j=0;j<8;++j) sm[(c0+j)*133 + p] = acc[j][i];  // T1c [c*133+p]
    }
  }
  __syncthreads();
  if (tid < 128){
    int p = tid, k = p & 15, lglob = pblk*8 + (p>>4);
    float a2[8];
    {
      const float* xp = ws + OFF_X2 + ((size_t)b*64+lglob)*8;
      const float* yp = ws + OFF_Y2 + ((size_t)b*16+k)*8;
      float4 x0_ = *(const float4*)&xp[0];
      float4 x1_ = *(const float4*)&xp[4];
      float4 y0_ = *(const float4*)&yp[0];
      float4 y1_ = *(const float4*)&yp[4];
      a2[0]=x0_.x+y0_.x; a2[1]=x0_.y+y0_.y; a2[2]=x0_.z+y0_.z; a2[3]=x0_.w+y0_.w;
      a2[4]=x1_.x+y1_.x; a2[5]=x1_.y+y1_.y; a2[6]=x1_.z+y1_.z; a2[7]=x1_.w+y1_.w;
    }
    for (int c=0;c<64;++c){
      float tn = sm[9024+c]*sm[c*133+p] + sm[9088+c];   // s1*T1+t1
      #pragma unroll
      for (int o2=0;o2<8;++o2) a2[o2] += sm[8512+o2*64+c]*tn;
    }
    float nrm=0.f;
    #pragma unroll
    for (int o2=0;o2<8;++o2) nrm += a2[o2]*a2[o2];
    float inv = 1.0f/sqrtf(nrm);
    size_t pos = (size_t)b*PPP + lglob*KKK + k;
    if (interleaved){
      long long idx = (long long)pos*8;
      if (idx+8 <= out_cap){
        *(float4*)&out[idx]   = make_float4(a2[0]*inv, a2[4]*inv, a2[1]*inv, a2[5]*inv);
        *(float4*)&out[idx+4] = make_float4(a2[2]*inv, a2[6]*inv, a2[3]*inv, a2[7]*inv);
      }
    } else {
      long long idx = (long long)pos*4;
      if (idx+4 <= out_cap)
        *(float4*)&out[idx] = make_float4(a2[0]*inv, a2[1]*inv, a2[2]*inv, a2[3]*inv);
    }
  }
}

extern "C" void kernel_launch(void* const* d_in, const int* in_sizes, int n_in,
                              void* d_out, int out_size, void* d_ws, size_t ws_size,
                              hipStream_t stream) {
  if (n_in < 15) return;
  if (in_sizes[0] != BRR*4096 || in_sizes[1] != BRR*4096) return;
  if (in_sizes[4] != 512)  return;   // P4_0 (64,8)
  if (in_sizes[7] != 4096) return;   // P1_1 (64,64)
  if (in_sizes[12] != 512) return;   // P1_2 (8,64)
  if (ws_size < (size_t)WS_FLOATS*4) return;   // clean fail, not a fault

  const float* Hr   = (const float*)d_in[0];
  const float* Hi   = (const float*)d_in[1];
  const float* P4_0 = (const float*)d_in[4];
  const float* g0   = (const float*)d_in[5];
  const float* b0   = (const float*)d_in[6];
  const float* P1_1 = (const float*)d_in[7];
  const float* P2_1 = (const float*)d_in[8];
  const float* P4_1 = (const float*)d_in[9];
  const float* g1   = (const float*)d_in[10];
  const float* b1   = (const float*)d_in[11];
  const float* P1_2 = (const float*)d_in[12];
  const float* P2_2 = (const float*)d_in[13];
  const float* P4_2 = (const float*)d_in[14];
  float* ws  = (float*)d_ws;
  float* out = (float*)d_out;
  int interleaved = (out_size >= 4194304) ? 1 : 0;

  k_zero<<<516, 256, 0, stream>>>((float4*)(ws + OFF_M1K), (524288+4096)/4);
  k_prep<<<BRR, 256, 0, stream>>>(Hr, Hi, P4_0, ws);
  k_bn<<<1, 64, 0, stream>>>(ws, g0, b0, OFF_SUM0, OFF_S0);
  k_xy1<<<2560, 256, 0, stream>>>(ws, P2_1, P4_1);
  k_pass1<<<BRR*8, 256, 0, stream>>>(ws, P1_1, P4_0);
  k_bn<<<1, 64, 0, stream>>>(ws, g1, b1, OFF_SUM1, OFF_S1);
  k_xy2s<<<BRR, 256, 0, stream>>>(ws, P2_2, P4_2);
  k_final<<<BRR*8, 256, 0, stream>>>(ws, P1_1, P4_0, P1_2, out,
                                     (long long)out_size, interleaved);
}

// Round 2
// 1088.353 us; speedup vs baseline: 2.3589x; 2.3589x over previous
//
#include <hip/hip_runtime.h>
#include <math.h>

#define BRR 512
#define LLL 64
#define KKK 16
#define EEE 64
#define CC2 8
#define PPP 1024
#define BN_EPS 1e-5f
#define NSTRIPE 16

__device__ __forceinline__ float relu_f(float v){ return v>0.f?v:0.f; }
// Row-padded W1 layout: stride 68 + 4-float stagger per 8-row octet.
__device__ __forceinline__ int lds_row(int r){ return r*68 + (((r>>3)&7)<<2); }

// ---- d_ws float layout ----
#define OFF_HBL  0u          // [(b*64+l)*8+c2]            262144
#define OFF_HBK  262144u     // [(b*16+k)*8+c2]             65536
#define OFF_Y0   327680u     // [b*1024 + k*64+c]          524288
#define OFF_X1   851968u     // [(b*64+l)*64+c] M0L->X1   2097152
#define OFF_Y1   2949120u    // [b*1024 + k*64+o] M0K->Y1  524288
#define OFF_X2   3473408u    // [(b*64+l)*8+o2]            262144
#define OFF_Y2   3735552u    // [(b*16+k)*8+o2]             65536
#define OFF_M1L  3801088u    // [b*4096 + l*64+c] raw k-mean of T1   2097152
#define OFF_M1K  5898240u    // [b*1024 + k*64+c] raw l-mean (plain) 524288
#define OFF_SUM0 6422528u
#define OFF_SSQ0 6423552u
#define OFF_SUM1 6424576u
#define OFF_SSQ1 6425600u
#define OFF_S0   6426624u
#define OFF_T0   6426688u
#define OFF_S1   6426752u
#define OFF_T1   6426816u
#define WS_FLOATS 6426880u   // 25,707,520 bytes

// ---------------------------------------------------------------------------
// K0: zero stat accumulators only (4096 floats). No atomics anywhere else now.
__global__ void k_zero(float4* __restrict__ p, int n4){
  int t = blockIdx.x*256 + threadIdx.x;
  if (t < n4) p[t] = make_float4(0.f,0.f,0.f,0.f);
}

// K1: per-b prep. HbL,HbK,y0,M0K,M0L + BN0 channel sums. All inputs f32.
__global__ __launch_bounds__(256) void k_prep(const float* __restrict__ Hr,
                                              const float* __restrict__ Hi,
                                              const float* __restrict__ P40,
                                              float* __restrict__ ws){
  __shared__ float sm[9344];
  int b = blockIdx.x, tid = threadIdx.x;
  const float* hrg = Hr + (size_t)b*4096;
  const float* hig = Hi + (size_t)b*4096;
  for (int t=tid;t<4096;t+=256){ sm[t]=hrg[t]; sm[4096+t]=hig[t]; }
  for (int t=tid;t<512;t+=256){ int c=t&63,j=t>>6; sm[8192+j*64+c]=P40[c*8+j]; }
  __syncthreads();
  for (int t=tid;t<512;t+=256){ int l=t>>3,c2=t&7;          // HbL [8704,9216)
    const float* src=sm+((c2<4)?0:4096); int u=c2&3;
    float s=0.f;
    #pragma unroll
    for(int k=0;k<16;++k) s+=src[(l*16+k)*4+u];
    sm[8704+t]=s*(1.f/16.f); }
  for (int t=tid;t<128;t+=256){ int k=t>>3,c2=t&7;          // HbK [9216,9344)
    const float* src=sm+((c2<4)?0:4096); int u=c2&3;
    float s=0.f;
    for(int l=0;l<64;++l) s+=src[(l*16+k)*4+u];
    sm[9216+t]=s*(1.f/64.f); }
  __syncthreads();
  for (int t=tid;t<1024;t+=256){ int k=t>>6,c=t&63; float s=0.f;   // y0 [4096,5120)
    #pragma unroll
    for(int j=0;j<8;++j) s+=sm[8192+j*64+c]*sm[9216+k*8+j];
    sm[4096+t]=0.1f*s; }
  for (int t=tid;t<4096;t+=256){ int l=t>>6,c=t&63; float s=0.f;   // x0 [0,4096)
    #pragma unroll
    for(int j=0;j<8;++j) s+=sm[8192+j*64+c]*sm[8704+l*8+j];
    sm[t]=0.1f*s; }
  __syncthreads();
  for (int t=tid;t<1024;t+=256){ int c=t&63; float yv=sm[4096+t]; float s=0.f;  // M0K [5120,6144)
    for(int l=0;l<64;++l) s+=relu_f(sm[l*64+c]+yv);
    sm[5120+t]=s*(1.f/64.f); }
  float ssum=0.f, ssq=0.f;                       // channel c = tid&63 (stride 256 preserves it)
  for (int t=tid;t<4096;t+=256){ int c=t&63; float xv=sm[t]; float s=0.f;
    #pragma unroll
    for(int k=0;k<16;++k){ float v=relu_f(xv+sm[4096+k*64+c]); s+=v; ssq+=v*v; }
    ssum+=s;
    ws[OFF_X1+(size_t)b*4096+t]=s*(1.f/16.f); }  // M0L
  __syncthreads();
  sm[6144+tid]=ssum; sm[6400+tid]=ssq;
  __syncthreads();
  if (tid<64){
    float ts =sm[6144+tid]+sm[6208+tid]+sm[6272+tid]+sm[6336+tid];
    float tss=sm[6400+tid]+sm[6464+tid]+sm[6528+tid]+sm[6592+tid];
    int stripe = b & (NSTRIPE-1);
    atomicAdd(&ws[OFF_SUM0+stripe*64+tid], ts);
    atomicAdd(&ws[OFF_SSQ0+stripe*64+tid], tss);
  }
  for (int t=tid;t<512;t+=256)  ws[OFF_HBL+(size_t)b*512+t]=sm[8704+t];
  for (int t=tid;t<128;t+=256)  ws[OFF_HBK+(size_t)b*128+t]=sm[9216+t];
  for (int t=tid;t<1024;t+=256) ws[OFF_Y0+(size_t)b*1024+t]=sm[4096+t];
  for (int t=tid;t<1024;t+=256) ws[OFF_Y1+(size_t)b*1024+t]=sm[5120+t];   // M0K
}

// K2: finalize BN -> s,t.
__global__ void k_bn(float* __restrict__ ws, const float* __restrict__ g_,
                     const float* __restrict__ b_, unsigned sumOff, unsigned outOff){
  int tid = threadIdx.x;
  if (tid < 64){
    float s=0.f, ss=0.f;
    for (int i=0;i<NSTRIPE;++i){ s+=ws[sumOff+i*64+tid]; ss+=ws[sumOff+1024+i*64+tid]; }
    const float invN = 1.0f/((float)BRR*LLL*KKK);
    float mu=s*invN, var=ss*invN-mu*mu;
    float sc = g_[tid]/sqrtf(var+BN_EPS);
    ws[outOff+tid]=sc;
    ws[outOff+64+tid]=b_[tid]-mu*sc;
  }
}

// K3: X1/Y1 in place over M0L/M0K.
__global__ __launch_bounds__(256) void k_xy1(float* __restrict__ ws,
                                             const float* __restrict__ P21,
                                             const float* __restrict__ P41){
  __shared__ float wt[4096], p41[512], mrow[1024], hbs[128], s0l[64], t0l[64];
  int bx = blockIdx.x, tid = threadIdx.x;
  for (int t=tid;t<4096;t+=256) wt[t] = 2.0f*P21[(t&63)*64 + (t>>6)];  // [c*64+o]
  for (int t=tid;t<512;t+=256)  p41[t] = P41[t];                        // [o*8+j]
  if (tid<64){ s0l[tid]=ws[OFF_S0+tid]; t0l[tid]=ws[OFF_T0+tid]; }
  bool isX = bx < 2048;
  int row0 = isX ? bx*16 : (bx-2048)*16;
  if (isX){
    for (int t=tid;t<1024;t+=256) mrow[t] = ws[OFF_X1+(size_t)row0*64+t];
    if (tid<128) hbs[tid] = ws[OFF_HBL+(size_t)row0*8+tid];
  } else {
    for (int t=tid;t<1024;t+=256) mrow[t] = ws[OFF_Y1+(size_t)row0*64+t];
    if (tid<128) hbs[tid] = ws[OFF_HBK+(size_t)row0*8+tid];
  }
  __syncthreads();
  for (int t=tid;t<1024;t+=256){ int c=t&63; mrow[t]=s0l[c]*mrow[t]+t0l[c]; }
  __syncthreads();
  int r4 = tid>>6, o = tid&63;
  #pragma unroll
  for (int rr=0;rr<4;++rr){
    int rl = rr*4 + r4;
    float s=0.f;
    for (int c=0;c<64;++c) s += wt[c*64+o]*mrow[rl*64+c];
    float s2=0.f;
    #pragma unroll
    for (int j=0;j<8;++j) s2 += p41[o*8+j]*hbs[rl*8+j];
    float res = s + 0.1f*s2;
    if (isX) ws[OFF_X1+(size_t)(row0+rl)*64+o] = res;
    else     ws[OFF_Y1+(size_t)(row0+rl)*64+o] = res;
  }
}

// ---- T1 tile LDS map (shared by k_pass1 loop body and k_final's t1_tile) ----
#define T_W1   0
#define T_X08  4384
#define T_Y0   4896
#define T_X1   5984
#define T_Y1   6496
#define T_S0   7520
#define T_T0   7584
#define T_P4T0 7648
#define T_HB8  8160
#define T_END  8224

__device__ void t1_tile(float* sm, const float* __restrict__ ws,
                        const float* __restrict__ P11, const float* __restrict__ P40,
                        int b, int pblk, int tid,
                        float acc[8][4], int og, int pg, int lloc, int c0){
  for (int t=tid;t<4096;t+=256){ int o=t>>6,c=t&63; sm[T_W1+lds_row(o)+c]=2.0f*P11[t]; }
  for (int t=tid;t<1024;t+=256){ int k=t>>6,c=t&63; sm[T_Y0+k*68+c]=ws[OFF_Y0+(size_t)b*1024+t]; }
  for (int t=tid;t<512;t+=256)  sm[T_X1+t]=ws[OFF_X1+((size_t)b*64+pblk*8)*64+t];
  for (int t=tid;t<1024;t+=256) sm[T_Y1+t]=ws[OFF_Y1+(size_t)b*1024+t];
  for (int t=tid;t<512;t+=256){ int c=t&63,j=t>>6; sm[T_P4T0+j*64+c]=P40[c*8+j]; }
  if (tid<64){ sm[T_S0+tid]=ws[OFF_S0+tid]; sm[T_T0+tid]=ws[OFF_T0+tid]; }
  else if (tid<128){ int t2=tid-64; sm[T_HB8+t2]=ws[OFF_HBL+((size_t)b*64+pblk*8)*8+t2]; }
  __syncthreads();
  for (int e=tid;e<512;e+=256){ int l=e>>6,c=e&63; float s=0.f;
    #pragma unroll
    for(int j=0;j<8;++j) s += sm[T_P4T0+j*64+c]*sm[T_HB8+l*8+j];
    sm[T_X08+e]=0.1f*s; }
  __syncthreads();
  {
    float xb[8];
    *(float4*)&xb[0] = *(const float4*)&sm[T_X1 + lloc*64 + c0];
    *(float4*)&xb[4] = *(const float4*)&sm[T_X1 + lloc*64 + c0 + 4];
    #pragma unroll
    for (int i=0;i<4;++i){
      int k=(pg&3)*4+i;
      float yb[8];
      *(float4*)&yb[0] = *(const float4*)&sm[T_Y1 + k*64 + c0];
      *(float4*)&yb[4] = *(const float4*)&sm[T_Y1 + k*64 + c0 + 4];
      #pragma unroll
      for (int j=0;j<8;++j) acc[j][i]=xb[j]+yb[j];
    }
  }
  #pragma unroll
  for (int c4=0;c4<16;++c4){
    float4 xr  = *(const float4*)&sm[T_X08 + lloc*64 + c4*4];
    float4 s0v = *(const float4*)&sm[T_S0 + c4*4];
    float4 t0v = *(const float4*)&sm[T_T0 + c4*4];
    float4 aa[4];
    #pragma unroll
    for (int i=0;i<4;++i){
      int k=(pg&3)*4+i;
      float4 yr = *(const float4*)&sm[T_Y0 + k*68 + c4*4];
      aa[i].x = s0v.x*relu_f(xr.x+yr.x)+t0v.x;
      aa[i].y = s0v.y*relu_f(xr.y+yr.y)+t0v.y;
      aa[i].z = s0v.z*relu_f(xr.z+yr.z)+t0v.z;
      aa[i].w = s0v.w*relu_f(xr.w+yr.w)+t0v.w;
    }
    #pragma unroll
    for (int j=0;j<8;++j){
      float4 w = *(const float4*)&sm[T_W1 + lds_row(c0+j) + c4*4];
      #pragma unroll
      for (int i=0;i<4;++i)
        acc[j][i] += w.x*aa[i].x + w.y*aa[i].y + w.z*aa[i].z + w.w*aa[i].w;
    }
  }
  #pragma unroll
  for (int j=0;j<8;++j)
    #pragma unroll
    for (int i=0;i<4;++i) acc[j][i] = relu_f(acc[j][i]);
}

// K4: ONE block per b, looping all 8 pblk slices. M1K accumulates in LDS
// (single owner thread per cell -> plain +=, ZERO global atomics; the round-1
// global atomicAdd caused 5.5 GB/dispatch of cross-XCD coherence thrash).
// MK layout: [wv][ (og*4+kg)*33 + i*8 + j ] -> writer hits all 32 banks
// (perfect spread), reader 2-way (free). W1/Y0/Y1 staged once per b.
#define MK_OFF 8224   // 4 wave-accumulators, 1088 floats each: [8224,12576)
__global__ __launch_bounds__(256,2) void k_pass1(float* __restrict__ ws,
                                                 const float* __restrict__ P11,
                                                 const float* __restrict__ P40){
  __shared__ float sm[12576];
  int b=blockIdx.x, tid=threadIdx.x;
  int og=tid&7, pg=tid>>3, lloc=pg>>2, kg=pg&3, c0=og*8, wv=tid>>6;
  // invariant staging (once per b)
  for (int t=tid;t<4096;t+=256){ int o=t>>6,c=t&63; sm[T_W1+lds_row(o)+c]=2.0f*P11[t]; }
  for (int t=tid;t<1024;t+=256){ int k=t>>6,c=t&63; sm[T_Y0+k*68+c]=ws[OFF_Y0+(size_t)b*1024+t]; }
  for (int t=tid;t<1024;t+=256) sm[T_Y1+t]=ws[OFF_Y1+(size_t)b*1024+t];
  for (int t=tid;t<512;t+=256){ int c=t&63,j=t>>6; sm[T_P4T0+j*64+c]=P40[c*8+j]; }
  if (tid<64){ sm[T_S0+tid]=ws[OFF_S0+tid]; sm[T_T0+tid]=ws[OFF_T0+tid]; }
  for (int t=tid;t<4352;t+=256) sm[MK_OFF+t]=0.f;
  float qsum[8];
  #pragma unroll
  for (int j=0;j<8;++j) qsum[j]=0.f;
  #pragma unroll 1
  for (int pblk=0;pblk<8;++pblk){
    __syncthreads();   // prev iter's X1/X08 reads done (and initial staging)
    for (int t=tid;t<512;t+=256) sm[T_X1+t]=ws[OFF_X1+((size_t)b*64+pblk*8)*64+t];
    if (tid<64) sm[T_HB8+tid]=ws[OFF_HBL+((size_t)b*64+pblk*8)*8+tid];
    __syncthreads();
    for (int e=tid;e<512;e+=256){ int l=e>>6,c=e&63; float s=0.f;
      #pragma unroll
      for(int j=0;j<8;++j) s += sm[T_P4T0+j*64+c]*sm[T_HB8+l*8+j];
      sm[T_X08+e]=0.1f*s; }
    __syncthreads();
    float acc[8][4];
    {
      float xb[8];
      *(float4*)&xb[0] = *(const float4*)&sm[T_X1 + lloc*64 + c0];
      *(float4*)&xb[4] = *(const float4*)&sm[T_X1 + lloc*64 + c0 + 4];
      #pragma unroll
      for (int i=0;i<4;++i){
        int k=kg*4+i;
        float yb[8];
        *(float4*)&yb[0] = *(const float4*)&sm[T_Y1 + k*64 + c0];
        *(float4*)&yb[4] = *(const float4*)&sm[T_Y1 + k*64 + c0 + 4];
        #pragma unroll
        for (int j=0;j<8;++j) acc[j][i]=xb[j]+yb[j];
      }
    }
    #pragma unroll
    for (int c4=0;c4<16;++c4){
      float4 xr  = *(const float4*)&sm[T_X08 + lloc*64 + c4*4];
      float4 s0v = *(const float4*)&sm[T_S0 + c4*4];
      float4 t0v = *(const float4*)&sm[T_T0 + c4*4];
      float4 aa[4];
      #pragma unroll
      for (int i=0;i<4;++i){
        int k=kg*4+i;
        float4 yr = *(const float4*)&sm[T_Y0 + k*68 + c4*4];
        aa[i].x = s0v.x*relu_f(xr.x+yr.x)+t0v.x;
        aa[i].y = s0v.y*relu_f(xr.y+yr.y)+t0v.y;
        aa[i].z = s0v.z*relu_f(xr.z+yr.z)+t0v.z;
        aa[i].w = s0v.w*relu_f(xr.w+yr.w)+t0v.w;
      }
      #pragma unroll
      for (int j=0;j<8;++j){
        float4 w = *(const float4*)&sm[T_W1 + lds_row(c0+j) + c4*4];
        #pragma unroll
        for (int i=0;i<4;++i)
          acc[j][i] += w.x*aa[i].x + w.y*aa[i].y + w.z*aa[i].z + w.w*aa[i].w;
      }
    }
    #pragma unroll
    for (int j=0;j<8;++j)
      #pragma unroll
      for (int i=0;i<4;++i) acc[j][i] = relu_f(acc[j][i]);
    // ---- stats: ssq accumulates in regs; row-sums feed M1L ----
    float sj[8];
    #pragma unroll
    for (int j=0;j<8;++j){
      sj[j]=acc[j][0]+acc[j][1]+acc[j][2]+acc[j][3];
      qsum[j]+=acc[j][0]*acc[j][0]+acc[j][1]*acc[j][1]+acc[j][2]*acc[j][2]+acc[j][3]*acc[j][3];
    }
    // M1L: k-reduce over kg (tid bits 3,4), write by kg==0 lanes
    #pragma unroll
    for (int j=0;j<8;++j){
      float r=sj[j];
      r += __shfl_xor(r, 8, 64);
      r += __shfl_xor(r, 16, 64);
      sj[j]=r;
    }
    if (kg==0){
      const float inv16 = 1.f/16.f;
      float4 v0 = make_float4(sj[0]*inv16, sj[1]*inv16, sj[2]*inv16, sj[3]*inv16);
      float4 v1 = make_float4(sj[4]*inv16, sj[5]*inv16, sj[6]*inv16, sj[7]*inv16);
      size_t base = OFF_M1L + ((size_t)b*64 + pblk*8 + lloc)*64 + c0;
      *(float4*)&ws[base]   = v0;
      *(float4*)&ws[base+4] = v1;
    }
    // M1K: lloc-pair sum via shfl (tid bit5 = lloc bit0), LDS += by owner lane
    #pragma unroll
    for (int j=0;j<8;++j){
      #pragma unroll
      for (int i=0;i<4;++i){
        float v = acc[j][i] + __shfl_xor(acc[j][i], 32, 64);
        if ((tid & 32)==0)
          sm[MK_OFF + wv*1088 + (og*4+kg)*33 + i*8 + j] += v;
      }
    }
  }
  __syncthreads();
  // M1K finalize (plain store) + BN1 channel sum from the same accumulator
  float tsacc=0.f;
  #pragma unroll
  for (int r=0;r<4;++r){
    int e = tid + r*256;
    int k=e>>6, c=e&63;
    int a = ((c>>3)*4+(k>>2))*33 + (k&3)*8 + (c&7);
    float v = sm[MK_OFF+a]+sm[MK_OFF+1088+a]+sm[MK_OFF+2176+a]+sm[MK_OFF+3264+a];
    tsacc += v;
    ws[OFF_M1K+(size_t)b*1024+e] = v*(1.f/64.f);
  }
  __syncthreads();   // mk reads done -> overlay stats
  sm[8224 + (tid&63)*5 + wv] = tsacc;
  #pragma unroll
  for (int j=0;j<8;++j) sm[8544+(c0+j)*33+pg] = qsum[j];
  __syncthreads();
  if (tid<64){
    float ts  = sm[8224+tid*5+0]+sm[8224+tid*5+1]+sm[8224+tid*5+2]+sm[8224+tid*5+3];
    float tss = 0.f;
    for (int g=0; g<32; ++g) tss += sm[8544+tid*33+g];
    int stripe = b & (NSTRIPE-1);
    atomicAdd(&ws[OFF_SUM1+stripe*64+tid], ts);
    atomicAdd(&ws[OFF_SSQ1+stripe*64+tid], tss);
  }
}

// K5: tiny per-b pass: X2/Y2 from raw M1L/M1K + BN1 affine. No atomics.
__global__ __launch_bounds__(256) void k_xy2s(float* __restrict__ ws,
                                              const float* __restrict__ P22,
                                              const float* __restrict__ P42){
  __shared__ float mln[4352];   // [l][68] : s1*M1L+t1
  __shared__ float mkn[1088];   // [k][68] : s1*M1K+t1
  __shared__ float w2[512];     // [c*8+o2] = 2*P22[o2][c]
  __shared__ float p42s[64];    // [o2*8+j]
  __shared__ float hbl[512];    // [l*8+j]
  __shared__ float hbk[128];    // [k*8+j]
  __shared__ float s1l[64], t1l[64];
  int b = blockIdx.x, tid = threadIdx.x;
  if (tid<64){ s1l[tid]=ws[OFF_S1+tid]; t1l[tid]=ws[OFF_T1+tid]; }
  for (int t=tid;t<512;t+=256) w2[t] = 2.0f*P22[(t&7)*64 + (t>>3)];
  if (tid<64) p42s[tid] = P42[tid];
  for (int t=tid;t<512;t+=256) hbl[t] = ws[OFF_HBL+(size_t)b*512+t];
  if (tid<128) hbk[tid] = ws[OFF_HBK+(size_t)b*128+tid];
  __syncthreads();
  for (int t=tid;t<4096;t+=256){ int l=t>>6,c=t&63;
    mln[l*68+c] = s1l[c]*ws[OFF_M1L+(size_t)b*4096+t] + t1l[c]; }
  for (int t=tid;t<1024;t+=256){ int k=t>>6,c=t&63;
    mkn[k*68+c] = s1l[c]*ws[OFF_M1K+(size_t)b*1024+t] + t1l[c]; }
  __syncthreads();
  for (int t=tid;t<512;t+=256){
    int l=t>>3, o2=t&7;
    float s=0.f;
    for (int c=0;c<64;++c) s += w2[c*8+o2]*mln[l*68+c];
    float s2=0.f;
    #pragma unroll
    for (int j=0;j<8;++j) s2 += p42s[o2*8+j]*hbl[l*8+j];
    ws[OFF_X2+(size_t)b*512+t] = s + 0.1f*s2;
  }
  if (tid<128){
    int k=tid>>3, o2=tid&7;
    float s=0.f;
    for (int c=0;c<64;++c) s += w2[c*8+o2]*mkn[k*68+c];
    float s2=0.f;
    #pragma unroll
    for (int j=0;j<8;++j) s2 += p42s[o2*8+j]*hbk[k*8+j];
    ws[OFF_Y2+(size_t)b*128+tid] = s + 0.1f*s2;
  }
}

// K6: tile pass + layer-2 + normalize + output (unchanged).
__global__ __launch_bounds__(256) void k_final(const float* __restrict__ ws,
                                               const float* __restrict__ P11,
                                               const float* __restrict__ P40,
                                               const float* __restrict__ P12,
                                               float* __restrict__ out,
                                               long long out_cap, int interleaved){
  __shared__ float sm[9152];   // T1c [0,8512); W2l [8512,9024); s1 [9024); t1 [9088)
  int bid=blockIdx.x, b=bid>>3, pblk=bid&7, tid=threadIdx.x;
  int og=tid&7, pg=tid>>3, lloc=pg>>2, c0=og*8;
  for (int t=tid;t<512;t+=256) sm[8512+t] = 2.0f*P12[t];   // [o2*64+c]
  if (tid<64) sm[9024+tid]=ws[OFF_S1+tid];
  else if (tid<128) sm[9088+(tid-64)]=ws[OFF_T1+(tid-64)];
  float acc[8][4];
  t1_tile(sm, ws, P11, P40, b, pblk, tid, acc, og, pg, lloc, c0);
  __syncthreads();
  {
    int kg = pg&3;
    #pragma unroll
    for (int i=0;i<4;++i){
      int p = lloc*16 + kg*4 + i;
      #pragma unroll
      for (int j=0;j<8;++j) sm[(c0+j)*133 + p] = acc[j][i];  // T1c [c*133+p]
    }
  }
  __syncthreads();
  if (tid < 128){
    int p = tid, k = p & 15, lglob = pblk*8 + (p>>4);
    float a2[8];
    {
      const float* xp = ws + OFF_X2 + ((size_t)b*64+lglob)*8;
      const float* yp = ws + OFF_Y2 + ((size_t)b*16+k)*8;
      float4 x0_ = *(const float4*)&xp[0];
      float4 x1_ = *(const float4*)&xp[4];
      float4 y0_ = *(const float4*)&yp[0];
      float4 y1_ = *(const float4*)&yp[4];
      a2[0]=x0_.x+y0_.x; a2[1]=x0_.y+y0_.y; a2[2]=x0_.z+y0_.z; a2[3]=x0_.w+y0_.w;
      a2[4]=x1_.x+y1_.x; a2[5]=x1_.y+y1_.y; a2[6]=x1_.z+y1_.z; a2[7]=x1_.w+y1_.w;
    }
    for (int c=0;c<64;++c){
      float tn = sm[9024+c]*sm[c*133+p] + sm[9088+c];   // s1*T1+t1
      #pragma unroll
      for (int o2=0;o2<8;++o2) a2[o2] += sm[8512+o2*64+c]*tn;
    }
    float nrm=0.f;
    #pragma unroll
    for (int o2=0;o2<8;++o2) nrm += a2[o2]*a2[o2];
    float inv = 1.0f/sqrtf(nrm);
    size_t pos = (size_t)b*PPP + lglob*KKK + k;
    if (interleaved){
      long long idx = (long long)pos*8;
      if (idx+8 <= out_cap){
        *(float4*)&out[idx]   = make_float4(a2[0]*inv, a2[4]*inv, a2[1]*inv, a2[5]*inv);
        *(float4*)&out[idx+4] = make_float4(a2[2]*inv, a2[6]*inv, a2[3]*inv, a2[7]*inv);
      }
    } else {
      long long idx = (long long)pos*4;
      if (idx+4 <= out_cap)
        *(float4*)&out[idx] = make_float4(a2[0]*inv, a2[1]*inv, a2[2]*inv, a2[3]*inv);
    }
  }
}

extern "C" void kernel_launch(void* const* d_in, const int* in_sizes, int n_in,
                              void* d_out, int out_size, void* d_ws, size_t ws_size,
                              hipStream_t stream) {
  if (n_in < 15) return;
  if (in_sizes[0] != BRR*4096 || in_sizes[1] != BRR*4096) return;
  if (in_sizes[4] != 512)  return;   // P4_0 (64,8)
  if (in_sizes[7] != 4096) return;   // P1_1 (64,64)
  if (in_sizes[12] != 512) return;   // P1_2 (8,64)
  if (ws_size < (size_t)WS_FLOATS*4) return;   // clean fail, not a fault

  const float* Hr   = (const float*)d_in[0];
  const float* Hi   = (const float*)d_in[1];
  const float* P4_0 = (const float*)d_in[4];
  const float* g0   = (const float*)d_in[5];
  const float* b0   = (const float*)d_in[6];
  const float* P1_1 = (const float*)d_in[7];
  const float* P2_1 = (const float*)d_in[8];
  const float* P4_1 = (const float*)d_in[9];
  const float* g1   = (const float*)d_in[10];
  const float* b1   = (const float*)d_in[11];
  const float* P1_2 = (const float*)d_in[12];
  const float* P2_2 = (const float*)d_in[13];
  const float* P4_2 = (const float*)d_in[14];
  float* ws  = (float*)d_ws;
  float* out = (float*)d_out;
  int interleaved = (out_size >= 4194304) ? 1 : 0;

  k_zero<<<4, 256, 0, stream>>>((float4*)(ws + OFF_SUM0), 4096/4);
  k_prep<<<BRR, 256, 0, stream>>>(Hr, Hi, P4_0, ws);
  k_bn<<<1, 64, 0, stream>>>(ws, g0, b0, OFF_SUM0, OFF_S0);
  k_xy1<<<2560, 256, 0, stream>>>(ws, P2_1, P4_1);
  k_pass1<<<BRR, 256, 0, stream>>>(ws, P1_1, P4_0);
  k_bn<<<1, 64, 0, stream>>>(ws, g1, b1, OFF_SUM1, OFF_S1);
  k_xy2s<<<BRR, 256, 0, stream>>>(ws, P2_2, P4_2);
  k_final<<<BRR*8, 256, 0, stream>>>(ws, P1_1, P4_0, P1_2, out,
                                     (long long)out_size, interleaved);
}

// Round 3
// 622.050 us; speedup vs baseline: 4.1272x; 1.7496x over previous
//
#include <hip/hip_runtime.h>
#include <math.h>

#define BRR 512
#define LLL 64
#define KKK 16
#define EEE 64
#define CC2 8
#define PPP 1024
#define BN_EPS 1e-5f
#define NSTRIPE 16

__device__ __forceinline__ float relu_f(float v){ return v>0.f?v:0.f; }
// Row-padded W1 layout: stride 68 + 4-float stagger per 8-row octet.
__device__ __forceinline__ int lds_row(int r){ return r*68 + (((r>>3)&7)<<2); }

// ---- d_ws float layout ----
#define OFF_HBL  0u          // [(b*64+l)*8+c2]            262144
#define OFF_HBK  262144u     // [(b*16+k)*8+c2]             65536
#define OFF_Y0   327680u     // [b*1024 + k*64+c]          524288
#define OFF_X1   851968u     // [(b*64+l)*64+c] M0L->X1   2097152
#define OFF_Y1   2949120u    // [b*1024 + k*64+o] M0K->Y1  524288
#define OFF_X2   3473408u    // [(b*64+l)*8+o2]            262144
#define OFF_Y2   3735552u    // [(b*16+k)*8+o2]             65536
#define OFF_M1L  3801088u    // [b*4096 + l*64+c] raw k-mean of T1   2097152
#define OFF_M1K  5898240u    // [b*1024 + k*64+c] raw l-mean (plain) 524288
#define OFF_SUM0 6422528u
#define OFF_SSQ0 6423552u
#define OFF_SUM1 6424576u
#define OFF_SSQ1 6425600u
#define OFF_S0   6426624u
#define OFF_T0   6426688u
#define OFF_S1   6426752u
#define OFF_T1   6426816u
#define WS_FLOATS 6426880u   // 25,707,520 bytes

// ---------------------------------------------------------------------------
// K0: zero stat accumulators only (4096 floats).
__global__ void k_zero(float4* __restrict__ p, int n4){
  int t = blockIdx.x*256 + threadIdx.x;
  if (t < n4) p[t] = make_float4(0.f,0.f,0.f,0.f);
}

// K1: per-b prep. HbL,HbK,y0,M0K,M0L + BN0 channel sums. All inputs f32.
__global__ __launch_bounds__(256) void k_prep(const float* __restrict__ Hr,
                                              const float* __restrict__ Hi,
                                              const float* __restrict__ P40,
                                              float* __restrict__ ws){
  __shared__ float sm[9344];
  int b = blockIdx.x, tid = threadIdx.x;
  const float* hrg = Hr + (size_t)b*4096;
  const float* hig = Hi + (size_t)b*4096;
  for (int t=tid;t<4096;t+=256){ sm[t]=hrg[t]; sm[4096+t]=hig[t]; }
  for (int t=tid;t<512;t+=256){ int c=t&63,j=t>>6; sm[8192+j*64+c]=P40[c*8+j]; }
  __syncthreads();
  for (int t=tid;t<512;t+=256){ int l=t>>3,c2=t&7;          // HbL [8704,9216)
    const float* src=sm+((c2<4)?0:4096); int u=c2&3;
    float s=0.f;
    #pragma unroll
    for(int k=0;k<16;++k) s+=src[(l*16+k)*4+u];
    sm[8704+t]=s*(1.f/16.f); }
  for (int t=tid;t<128;t+=256){ int k=t>>3,c2=t&7;          // HbK [9216,9344)
    const float* src=sm+((c2<4)?0:4096); int u=c2&3;
    float s=0.f;
    for(int l=0;l<64;++l) s+=src[(l*16+k)*4+u];
    sm[9216+t]=s*(1.f/64.f); }
  __syncthreads();
  for (int t=tid;t<1024;t+=256){ int k=t>>6,c=t&63; float s=0.f;   // y0 [4096,5120)
    #pragma unroll
    for(int j=0;j<8;++j) s+=sm[8192+j*64+c]*sm[9216+k*8+j];
    sm[4096+t]=0.1f*s; }
  for (int t=tid;t<4096;t+=256){ int l=t>>6,c=t&63; float s=0.f;   // x0 [0,4096)
    #pragma unroll
    for(int j=0;j<8;++j) s+=sm[8192+j*64+c]*sm[8704+l*8+j];
    sm[t]=0.1f*s; }
  __syncthreads();
  for (int t=tid;t<1024;t+=256){ int c=t&63; float yv=sm[4096+t]; float s=0.f;  // M0K [5120,6144)
    for(int l=0;l<64;++l) s+=relu_f(sm[l*64+c]+yv);
    sm[5120+t]=s*(1.f/64.f); }
  float ssum=0.f, ssq=0.f;                       // channel c = tid&63 (stride 256 preserves it)
  for (int t=tid;t<4096;t+=256){ int c=t&63; float xv=sm[t]; float s=0.f;
    #pragma unroll
    for(int k=0;k<16;++k){ float v=relu_f(xv+sm[4096+k*64+c]); s+=v; ssq+=v*v; }
    ssum+=s;
    ws[OFF_X1+(size_t)b*4096+t]=s*(1.f/16.f); }  // M0L
  __syncthreads();
  sm[6144+tid]=ssum; sm[6400+tid]=ssq;
  __syncthreads();
  if (tid<64){
    float ts =sm[6144+tid]+sm[6208+tid]+sm[6272+tid]+sm[6336+tid];
    float tss=sm[6400+tid]+sm[6464+tid]+sm[6528+tid]+sm[6592+tid];
    int stripe = b & (NSTRIPE-1);
    atomicAdd(&ws[OFF_SUM0+stripe*64+tid], ts);
    atomicAdd(&ws[OFF_SSQ0+stripe*64+tid], tss);
  }
  for (int t=tid;t<512;t+=256)  ws[OFF_HBL+(size_t)b*512+t]=sm[8704+t];
  for (int t=tid;t<128;t+=256)  ws[OFF_HBK+(size_t)b*128+t]=sm[9216+t];
  for (int t=tid;t<1024;t+=256) ws[OFF_Y0+(size_t)b*1024+t]=sm[4096+t];
  for (int t=tid;t<1024;t+=256) ws[OFF_Y1+(size_t)b*1024+t]=sm[5120+t];   // M0K
}

// K2: finalize BN -> s,t.
__global__ void k_bn(float* __restrict__ ws, const float* __restrict__ g_,
                     const float* __restrict__ b_, unsigned sumOff, unsigned outOff){
  int tid = threadIdx.x;
  if (tid < 64){
    float s=0.f, ss=0.f;
    for (int i=0;i<NSTRIPE;++i){ s+=ws[sumOff+i*64+tid]; ss+=ws[sumOff+1024+i*64+tid]; }
    const float invN = 1.0f/((float)BRR*LLL*KKK);
    float mu=s*invN, var=ss*invN-mu*mu;
    float sc = g_[tid]/sqrtf(var+BN_EPS);
    ws[outOff+tid]=sc;
    ws[outOff+64+tid]=b_[tid]-mu*sc;
  }
}

// K3: X1/Y1 in place over M0L/M0K.
__global__ __launch_bounds__(256) void k_xy1(float* __restrict__ ws,
                                             const float* __restrict__ P21,
                                             const float* __restrict__ P41){
  __shared__ float wt[4096], p41[512], mrow[1024], hbs[128], s0l[64], t0l[64];
  int bx = blockIdx.x, tid = threadIdx.x;
  for (int t=tid;t<4096;t+=256) wt[t] = 2.0f*P21[(t&63)*64 + (t>>6)];  // [c*64+o]
  for (int t=tid;t<512;t+=256)  p41[t] = P41[t];                        // [o*8+j]
  if (tid<64){ s0l[tid]=ws[OFF_S0+tid]; t0l[tid]=ws[OFF_T0+tid]; }
  bool isX = bx < 2048;
  int row0 = isX ? bx*16 : (bx-2048)*16;
  if (isX){
    for (int t=tid;t<1024;t+=256) mrow[t] = ws[OFF_X1+(size_t)row0*64+t];
    if (tid<128) hbs[tid] = ws[OFF_HBL+(size_t)row0*8+tid];
  } else {
    for (int t=tid;t<1024;t+=256) mrow[t] = ws[OFF_Y1+(size_t)row0*64+t];
    if (tid<128) hbs[tid] = ws[OFF_HBK+(size_t)row0*8+tid];
  }
  __syncthreads();
  for (int t=tid;t<1024;t+=256){ int c=t&63; mrow[t]=s0l[c]*mrow[t]+t0l[c]; }
  __syncthreads();
  int r4 = tid>>6, o = tid&63;
  #pragma unroll
  for (int rr=0;rr<4;++rr){
    int rl = rr*4 + r4;
    float s=0.f;
    for (int c=0;c<64;++c) s += wt[c*64+o]*mrow[rl*64+c];
    float s2=0.f;
    #pragma unroll
    for (int j=0;j<8;++j) s2 += p41[o*8+j]*hbs[rl*8+j];
    float res = s + 0.1f*s2;
    if (isX) ws[OFF_X1+(size_t)(row0+rl)*64+o] = res;
    else     ws[OFF_Y1+(size_t)(row0+rl)*64+o] = res;
  }
}

// ---- T1 tile LDS map (shared by k_pass1 loop body and k_final's t1_tile) ----
#define T_W1   0
#define T_X08  4384
#define T_Y0   4896
#define T_X1   5984
#define T_Y1   6496
#define T_S0   7520
#define T_T0   7584
#define T_P4T0 7648
#define T_HB8  8160
#define T_END  8224

__device__ void t1_tile(float* sm, const float* __restrict__ ws,
                        const float* __restrict__ P11, const float* __restrict__ P40,
                        int b, int pblk, int tid,
                        float acc[8][4], int og, int pg, int lloc, int c0){
  for (int t=tid;t<4096;t+=256){ int o=t>>6,c=t&63; sm[T_W1+lds_row(o)+c]=2.0f*P11[t]; }
  for (int t=tid;t<1024;t+=256){ int k=t>>6,c=t&63; sm[T_Y0+k*68+c]=ws[OFF_Y0+(size_t)b*1024+t]; }
  for (int t=tid;t<512;t+=256)  sm[T_X1+t]=ws[OFF_X1+((size_t)b*64+pblk*8)*64+t];
  for (int t=tid;t<1024;t+=256) sm[T_Y1+t]=ws[OFF_Y1+(size_t)b*1024+t];
  for (int t=tid;t<512;t+=256){ int c=t&63,j=t>>6; sm[T_P4T0+j*64+c]=P40[c*8+j]; }
  if (tid<64){ sm[T_S0+tid]=ws[OFF_S0+tid]; sm[T_T0+tid]=ws[OFF_T0+tid]; }
  else if (tid<128){ int t2=tid-64; sm[T_HB8+t2]=ws[OFF_HBL+((size_t)b*64+pblk*8)*8+t2]; }
  __syncthreads();
  for (int e=tid;e<512;e+=256){ int l=e>>6,c=e&63; float s=0.f;
    #pragma unroll
    for(int j=0;j<8;++j) s += sm[T_P4T0+j*64+c]*sm[T_HB8+l*8+j];
    sm[T_X08+e]=0.1f*s; }
  __syncthreads();
  {
    float xb[8];
    *(float4*)&xb[0] = *(const float4*)&sm[T_X1 + lloc*64 + c0];
    *(float4*)&xb[4] = *(const float4*)&sm[T_X1 + lloc*64 + c0 + 4];
    #pragma unroll
    for (int i=0;i<4;++i){
      int k=(pg&3)*4+i;
      float yb[8];
      *(float4*)&yb[0] = *(const float4*)&sm[T_Y1 + k*64 + c0];
      *(float4*)&yb[4] = *(const float4*)&sm[T_Y1 + k*64 + c0 + 4];
      #pragma unroll
      for (int j=0;j<8;++j) acc[j][i]=xb[j]+yb[j];
    }
  }
  #pragma unroll
  for (int c4=0;c4<16;++c4){
    float4 xr  = *(const float4*)&sm[T_X08 + lloc*64 + c4*4];
    float4 s0v = *(const float4*)&sm[T_S0 + c4*4];
    float4 t0v = *(const float4*)&sm[T_T0 + c4*4];
    float4 aa[4];
    #pragma unroll
    for (int i=0;i<4;++i){
      int k=(pg&3)*4+i;
      float4 yr = *(const float4*)&sm[T_Y0 + k*68 + c4*4];
      aa[i].x = s0v.x*relu_f(xr.x+yr.x)+t0v.x;
      aa[i].y = s0v.y*relu_f(xr.y+yr.y)+t0v.y;
      aa[i].z = s0v.z*relu_f(xr.z+yr.z)+t0v.z;
      aa[i].w = s0v.w*relu_f(xr.w+yr.w)+t0v.w;
    }
    #pragma unroll
    for (int j=0;j<8;++j){
      float4 w = *(const float4*)&sm[T_W1 + lds_row(c0+j) + c4*4];
      #pragma unroll
      for (int i=0;i<4;++i)
        acc[j][i] += w.x*aa[i].x + w.y*aa[i].y + w.z*aa[i].z + w.w*aa[i].w;
    }
  }
  #pragma unroll
  for (int j=0;j<8;++j)
    #pragma unroll
    for (int i=0;i<4;++i) acc[j][i] = relu_f(acc[j][i]);
}

// K4: ONE block per b, looping all 8 pblk slices. M1K partials accumulate in
// PERSISTENT REGISTERS mk[8][4] (statically indexed; one shfl+LDS exchange at
// the END only). Plain __launch_bounds__(256): the round-2 (256,2) variant
// allocated 128 VGPRs and spilled acc to scratch -> 2.9 GB phantom HBM traffic.
#define MK_OFF 8224   // 4 wave-partials, 1088 floats each: [8224,12576)
__global__ __launch_bounds__(256) void k_pass1(float* __restrict__ ws,
                                               const float* __restrict__ P11,
                                               const float* __restrict__ P40){
  __shared__ float sm[12576];
  int b=blockIdx.x, tid=threadIdx.x;
  int og=tid&7, pg=tid>>3, lloc=pg>>2, kg=pg&3, c0=og*8, wv=tid>>6;
  // invariant staging (once per b)
  for (int t=tid;t<4096;t+=256){ int o=t>>6,c=t&63; sm[T_W1+lds_row(o)+c]=2.0f*P11[t]; }
  for (int t=tid;t<1024;t+=256){ int k=t>>6,c=t&63; sm[T_Y0+k*68+c]=ws[OFF_Y0+(size_t)b*1024+t]; }
  for (int t=tid;t<1024;t+=256) sm[T_Y1+t]=ws[OFF_Y1+(size_t)b*1024+t];
  for (int t=tid;t<512;t+=256){ int c=t&63,j=t>>6; sm[T_P4T0+j*64+c]=P40[c*8+j]; }
  if (tid<64){ sm[T_S0+tid]=ws[OFF_S0+tid]; sm[T_T0+tid]=ws[OFF_T0+tid]; }
  float qsum[8], mk[8][4];
  #pragma unroll
  for (int j=0;j<8;++j){ qsum[j]=0.f;
    #pragma unroll
    for (int i=0;i<4;++i) mk[j][i]=0.f; }
  #pragma unroll 1
  for (int pblk=0;pblk<8;++pblk){
    __syncthreads();   // prev iter's X1/X08 reads done (and initial staging)
    for (int t=tid;t<512;t+=256) sm[T_X1+t]=ws[OFF_X1+((size_t)b*64+pblk*8)*64+t];
    if (tid<64) sm[T_HB8+tid]=ws[OFF_HBL+((size_t)b*64+pblk*8)*8+tid];
    __syncthreads();
    for (int e=tid;e<512;e+=256){ int l=e>>6,c=e&63; float s=0.f;
      #pragma unroll
      for(int j=0;j<8;++j) s += sm[T_P4T0+j*64+c]*sm[T_HB8+l*8+j];
      sm[T_X08+e]=0.1f*s; }
    __syncthreads();
    float acc[8][4];
    {
      float xb[8];
      *(float4*)&xb[0] = *(const float4*)&sm[T_X1 + lloc*64 + c0];
      *(float4*)&xb[4] = *(const float4*)&sm[T_X1 + lloc*64 + c0 + 4];
      #pragma unroll
      for (int i=0;i<4;++i){
        int k=kg*4+i;
        float yb[8];
        *(float4*)&yb[0] = *(const float4*)&sm[T_Y1 + k*64 + c0];
        *(float4*)&yb[4] = *(const float4*)&sm[T_Y1 + k*64 + c0 + 4];
        #pragma unroll
        for (int j=0;j<8;++j) acc[j][i]=xb[j]+yb[j];
      }
    }
    #pragma unroll
    for (int c4=0;c4<16;++c4){
      float4 xr  = *(const float4*)&sm[T_X08 + lloc*64 + c4*4];
      float4 s0v = *(const float4*)&sm[T_S0 + c4*4];
      float4 t0v = *(const float4*)&sm[T_T0 + c4*4];
      float4 aa[4];
      #pragma unroll
      for (int i=0;i<4;++i){
        int k=kg*4+i;
        float4 yr = *(const float4*)&sm[T_Y0 + k*68 + c4*4];
        aa[i].x = s0v.x*relu_f(xr.x+yr.x)+t0v.x;
        aa[i].y = s0v.y*relu_f(xr.y+yr.y)+t0v.y;
        aa[i].z = s0v.z*relu_f(xr.z+yr.z)+t0v.z;
        aa[i].w = s0v.w*relu_f(xr.w+yr.w)+t0v.w;
      }
      #pragma unroll
      for (int j=0;j<8;++j){
        float4 w = *(const float4*)&sm[T_W1 + lds_row(c0+j) + c4*4];
        #pragma unroll
        for (int i=0;i<4;++i)
          acc[j][i] += w.x*aa[i].x + w.y*aa[i].y + w.z*aa[i].z + w.w*aa[i].w;
      }
    }
    #pragma unroll
    for (int j=0;j<8;++j)
      #pragma unroll
      for (int i=0;i<4;++i) acc[j][i] = relu_f(acc[j][i]);
    // ---- fold acc into running reductions (all in registers) ----
    float sj[8];
    #pragma unroll
    for (int j=0;j<8;++j){
      sj[j]=acc[j][0]+acc[j][1]+acc[j][2]+acc[j][3];
      qsum[j]+=acc[j][0]*acc[j][0]+acc[j][1]*acc[j][1]+acc[j][2]*acc[j][2]+acc[j][3]*acc[j][3];
      #pragma unroll
      for (int i=0;i<4;++i) mk[j][i]+=acc[j][i];
    }
    // M1L: k-reduce over kg (tid bits 3,4), write by kg==0 lanes
    #pragma unroll
    for (int j=0;j<8;++j){
      float r=sj[j];
      r += __shfl_xor(r, 8, 64);
      r += __shfl_xor(r, 16, 64);
      sj[j]=r;
    }
    if (kg==0){
      const float inv16 = 1.f/16.f;
      float4 v0 = make_float4(sj[0]*inv16, sj[1]*inv16, sj[2]*inv16, sj[3]*inv16);
      float4 v1 = make_float4(sj[4]*inv16, sj[5]*inv16, sj[6]*inv16, sj[7]*inv16);
      size_t base = OFF_M1L + ((size_t)b*64 + pblk*8 + lloc)*64 + c0;
      *(float4*)&ws[base]   = v0;
      *(float4*)&ws[base+4] = v1;
    }
  }
  // ---- M1K: lloc-pair sum via shfl (tid bit5 = lloc bit0), then 4-wave LDS
  //      exchange. Writer (og*4+kg)*33 stride hits all 32 banks. No zero-init
  //      needed: every cell has exactly one owner write.
  #pragma unroll
  for (int j=0;j<8;++j){
    #pragma unroll
    for (int i=0;i<4;++i){
      float v = mk[j][i] + __shfl_xor(mk[j][i], 32, 64);
      if ((tid & 32)==0)
        sm[MK_OFF + wv*1088 + (og*4+kg)*33 + i*8 + j] = v;
    }
  }
  __syncthreads();
  // M1K finalize (plain store) + BN1 channel sum from the same accumulator
  float tsacc=0.f;
  #pragma unroll
  for (int r=0;r<4;++r){
    int e = tid + r*256;
    int k=e>>6, c=e&63;
    int a = ((c>>3)*4+(k>>2))*33 + (k&3)*8 + (c&7);
    float v = sm[MK_OFF+a]+sm[MK_OFF+1088+a]+sm[MK_OFF+2176+a]+sm[MK_OFF+3264+a];
    tsacc += v;
    ws[OFF_M1K+(size_t)b*1024+e] = v*(1.f/64.f);
  }
  __syncthreads();   // mk reads done -> overlay stats
  sm[8224 + (tid&63)*5 + wv] = tsacc;
  #pragma unroll
  for (int j=0;j<8;++j) sm[8544+(c0+j)*33+pg] = qsum[j];
  __syncthreads();
  if (tid<64){
    float ts  = sm[8224+tid*5+0]+sm[8224+tid*5+1]+sm[8224+tid*5+2]+sm[8224+tid*5+3];
    float tss = 0.f;
    for (int g=0; g<32; ++g) tss += sm[8544+tid*33+g];
    int stripe = b & (NSTRIPE-1);
    atomicAdd(&ws[OFF_SUM1+stripe*64+tid], ts);
    atomicAdd(&ws[OFF_SSQ1+stripe*64+tid], tss);
  }
}

// K5: tiny per-b pass: X2/Y2 from raw M1L/M1K + BN1 affine. No atomics.
__global__ __launch_bounds__(256) void k_xy2s(float* __restrict__ ws,
                                              const float* __restrict__ P22,
                                              const float* __restrict__ P42){
  __shared__ float mln[4352];   // [l][68] : s1*M1L+t1
  __shared__ float mkn[1088];   // [k][68] : s1*M1K+t1
  __shared__ float w2[512];     // [c*8+o2] = 2*P22[o2][c]
  __shared__ float p42s[64];    // [o2*8+j]
  __shared__ float hbl[512];    // [l*8+j]
  __shared__ float hbk[128];    // [k*8+j]
  __shared__ float s1l[64], t1l[64];
  int b = blockIdx.x, tid = threadIdx.x;
  if (tid<64){ s1l[tid]=ws[OFF_S1+tid]; t1l[tid]=ws[OFF_T1+tid]; }
  for (int t=tid;t<512;t+=256) w2[t] = 2.0f*P22[(t&7)*64 + (t>>3)];
  if (tid<64) p42s[tid] = P42[tid];
  for (int t=tid;t<512;t+=256) hbl[t] = ws[OFF_HBL+(size_t)b*512+t];
  if (tid<128) hbk[tid] = ws[OFF_HBK+(size_t)b*128+tid];
  __syncthreads();
  for (int t=tid;t<4096;t+=256){ int l=t>>6,c=t&63;
    mln[l*68+c] = s1l[c]*ws[OFF_M1L+(size_t)b*4096+t] + t1l[c]; }
  for (int t=tid;t<1024;t+=256){ int k=t>>6,c=t&63;
    mkn[k*68+c] = s1l[c]*ws[OFF_M1K+(size_t)b*1024+t] + t1l[c]; }
  __syncthreads();
  for (int t=tid;t<512;t+=256){
    int l=t>>3, o2=t&7;
    float s=0.f;
    for (int c=0;c<64;++c) s += w2[c*8+o2]*mln[l*68+c];
    float s2=0.f;
    #pragma unroll
    for (int j=0;j<8;++j) s2 += p42s[o2*8+j]*hbl[l*8+j];
    ws[OFF_X2+(size_t)b*512+t] = s + 0.1f*s2;
  }
  if (tid<128){
    int k=tid>>3, o2=tid&7;
    float s=0.f;
    for (int c=0;c<64;++c) s += w2[c*8+o2]*mkn[k*68+c];
    float s2=0.f;
    #pragma unroll
    for (int j=0;j<8;++j) s2 += p42s[o2*8+j]*hbk[k*8+j];
    ws[OFF_Y2+(size_t)b*128+tid] = s + 0.1f*s2;
  }
}

// K6: tile pass + layer-2 + normalize + output (unchanged).
__global__ __launch_bounds__(256) void k_final(const float* __restrict__ ws,
                                               const float* __restrict__ P11,
                                               const float* __restrict__ P40,
                                               const float* __restrict__ P12,
                                               float* __restrict__ out,
                                               long long out_cap, int interleaved){
  __shared__ float sm[9152];   // T1c [0,8512); W2l [8512,9024); s1 [9024); t1 [9088)
  int bid=blockIdx.x, b=bid>>3, pblk=bid&7, tid=threadIdx.x;
  int og=tid&7, pg=tid>>3, lloc=pg>>2, c0=og*8;
  for (int t=tid;t<512;t+=256) sm[8512+t] = 2.0f*P12[t];   // [o2*64+c]
  if (tid<64) sm[9024+tid]=ws[OFF_S1+tid];
  else if (tid<128) sm[9088+(tid-64)]=ws[OFF_T1+(tid-64)];
  float acc[8][4];
  t1_tile(sm, ws, P11, P40, b, pblk, tid, acc, og, pg, lloc, c0);
  __syncthreads();
  {
    int kg = pg&3;
    #pragma unroll
    for (int i=0;i<4;++i){
      int p = lloc*16 + kg*4 + i;
      #pragma unroll
      for (int j=0;j<8;++j) sm[(c0+j)*133 + p] = acc[j][i];  // T1c [c*133+p]
    }
  }
  __syncthreads();
  if (tid < 128){
    int p = tid, k = p & 15, lglob = pblk*8 + (p>>4);
    float a2[8];
    {
      const float* xp = ws + OFF_X2 + ((size_t)b*64+lglob)*8;
      const float* yp = ws + OFF_Y2 + ((size_t)b*16+k)*8;
      float4 x0_ = *(const float4*)&xp[0];
      float4 x1_ = *(const float4*)&xp[4];
      float4 y0_ = *(const float4*)&yp[0];
      float4 y1_ = *(const float4*)&yp[4];
      a2[0]=x0_.x+y0_.x; a2[1]=x0_.y+y0_.y; a2[2]=x0_.z+y0_.z; a2[3]=x0_.w+y0_.w;
      a2[4]=x1_.x+y1_.x; a2[5]=x1_.y+y1_.y; a2[6]=x1_.z+y1_.z; a2[7]=x1_.w+y1_.w;
    }
    for (int c=0;c<64;++c){
      float tn = sm[9024+c]*sm[c*133+p] + sm[9088+c];   // s1*T1+t1
      #pragma unroll
      for (int o2=0;o2<8;++o2) a2[o2] += sm[8512+o2*64+c]*tn;
    }
    float nrm=0.f;
    #pragma unroll
    for (int o2=0;o2<8;++o2) nrm += a2[o2]*a2[o2];
    float inv = 1.0f/sqrtf(nrm);
    size_t pos = (size_t)b*PPP + lglob*KKK + k;
    if (interleaved){
      long long idx = (long long)pos*8;
      if (idx+8 <= out_cap){
        *(float4*)&out[idx]   = make_float4(a2[0]*inv, a2[4]*inv, a2[1]*inv, a2[5]*inv);
        *(float4*)&out[idx+4] = make_float4(a2[2]*inv, a2[6]*inv, a2[3]*inv, a2[7]*inv);
      }
    } else {
      long long idx = (long long)pos*4;
      if (idx+4 <= out_cap)
        *(float4*)&out[idx] = make_float4(a2[0]*inv, a2[1]*inv, a2[2]*inv, a2[3]*inv);
    }
  }
}

extern "C" void kernel_launch(void* const* d_in, const int* in_sizes, int n_in,
                              void* d_out, int out_size, void* d_ws, size_t ws_size,
                              hipStream_t stream) {
  if (n_in < 15) return;
  if (in_sizes[0] != BRR*4096 || in_sizes[1] != BRR*4096) return;
  if (in_sizes[4] != 512)  return;   // P4_0 (64,8)
  if (in_sizes[7] != 4096) return;   // P1_1 (64,64)
  if (in_sizes[12] != 512) return;   // P1_2 (8,64)
  if (ws_size < (size_t)WS_FLOATS*4) return;   // clean fail, not a fault

  const float* Hr   = (const float*)d_in[0];
  const float* Hi   = (const float*)d_in[1];
  const float* P4_0 = (const float*)d_in[4];
  const float* g0   = (const float*)d_in[5];
  const float* b0   = (const float*)d_in[6];
  const float* P1_1 = (const float*)d_in[7];
  const float* P2_1 = (const float*)d_in[8];
  const float* P4_1 = (const float*)d_in[9];
  const float* g1   = (const float*)d_in[10];
  const float* b1   = (const float*)d_in[11];
  const float* P1_2 = (const float*)d_in[12];
  const float* P2_2 = (const float*)d_in[13];
  const float* P4_2 = (const float*)d_in[14];
  float* ws  = (float*)d_ws;
  float* out = (float*)d_out;
  int interleaved = (out_size >= 4194304) ? 1 : 0;

  k_zero<<<4, 256, 0, stream>>>((float4*)(ws + OFF_SUM0), 4096/4);
  k_prep<<<BRR, 256, 0, stream>>>(Hr, Hi, P4_0, ws);
  k_bn<<<1, 64, 0, stream>>>(ws, g0, b0, OFF_SUM0, OFF_S0);
  k_xy1<<<2560, 256, 0, stream>>>(ws, P2_1, P4_1);
  k_pass1<<<BRR, 256, 0, stream>>>(ws, P1_1, P4_0);
  k_bn<<<1, 64, 0, stream>>>(ws, g1, b1, OFF_SUM1, OFF_S1);
  k_xy2s<<<BRR, 256, 0, stream>>>(ws, P2_2, P4_2);
  k_final<<<BRR*8, 256, 0, stream>>>(ws, P1_1, P4_0, P1_2, out,
                                     (long long)out_size, interleaved);
}

// Round 4
// 400.557 us; speedup vs baseline: 6.4093x; 1.5530x over previous
//
#include <hip/hip_runtime.h>
#include <math.h>

#define BRR 512
#define LLL 64
#define KKK 16
#define EEE 64
#define CC2 8
#define PPP 1024
#define BN_EPS 1e-5f
#define NSTRIPE 16

__device__ __forceinline__ float relu_f(float v){ return v>0.f?v:0.f; }
// Row-padded W1 layout: stride 68 + 4-float stagger per 8-row octet.
__device__ __forceinline__ int lds_row(int r){ return r*68 + (((r>>3)&7)<<2); }

// ---- d_ws float layout ----
#define OFF_HBL  0u          // [(b*64+l)*8+c2]            262144
#define OFF_HBK  262144u     // [(b*16+k)*8+c2]             65536
#define OFF_Y0   327680u     // [b*1024 + k*64+c]          524288
#define OFF_X1   851968u     // [(b*64+l)*64+c] M0L->X1   2097152
#define OFF_Y1   2949120u    // [b*1024 + k*64+o] M0K->Y1  524288
#define OFF_X2   3473408u    // [(b*64+l)*8+o2]            262144
#define OFF_Y2   3735552u    // [(b*16+k)*8+o2]             65536
#define OFF_M1L  3801088u    // [b*4096 + l*64+c] raw k-mean of T1   2097152
#define OFF_M1K  5898240u    // [b*1024 + k*64+c] raw l-mean (plain) 524288
#define OFF_SUM0 6422528u
#define OFF_SSQ0 6423552u
#define OFF_SUM1 6424576u
#define OFF_SSQ1 6425600u
#define OFF_S0   6426624u
#define OFF_T0   6426688u
#define OFF_S1   6426752u
#define OFF_T1   6426816u
#define WS_FLOATS 6426880u   // 25,707,520 bytes

// ---------------------------------------------------------------------------
// K0: zero stat accumulators only (4096 floats).
__global__ void k_zero(float4* __restrict__ p, int n4){
  int t = blockIdx.x*256 + threadIdx.x;
  if (t < n4) p[t] = make_float4(0.f,0.f,0.f,0.f);
}

// K1: per-b prep. HbL,HbK,y0,M0K,M0L + BN0 channel sums. All inputs f32.
__global__ __launch_bounds__(256) void k_prep(const float* __restrict__ Hr,
                                              const float* __restrict__ Hi,
                                              const float* __restrict__ P40,
                                              float* __restrict__ ws){
  __shared__ float sm[9344];
  int b = blockIdx.x, tid = threadIdx.x;
  const float* hrg = Hr + (size_t)b*4096;
  const float* hig = Hi + (size_t)b*4096;
  for (int t=tid;t<4096;t+=256){ sm[t]=hrg[t]; sm[4096+t]=hig[t]; }
  for (int t=tid;t<512;t+=256){ int c=t&63,j=t>>6; sm[8192+j*64+c]=P40[c*8+j]; }
  __syncthreads();
  for (int t=tid;t<512;t+=256){ int l=t>>3,c2=t&7;          // HbL [8704,9216)
    const float* src=sm+((c2<4)?0:4096); int u=c2&3;
    float s=0.f;
    #pragma unroll
    for(int k=0;k<16;++k) s+=src[(l*16+k)*4+u];
    sm[8704+t]=s*(1.f/16.f); }
  for (int t=tid;t<128;t+=256){ int k=t>>3,c2=t&7;          // HbK [9216,9344)
    const float* src=sm+((c2<4)?0:4096); int u=c2&3;
    float s=0.f;
    for(int l=0;l<64;++l) s+=src[(l*16+k)*4+u];
    sm[9216+t]=s*(1.f/64.f); }
  __syncthreads();
  for (int t=tid;t<1024;t+=256){ int k=t>>6,c=t&63; float s=0.f;   // y0 [4096,5120)
    #pragma unroll
    for(int j=0;j<8;++j) s+=sm[8192+j*64+c]*sm[9216+k*8+j];
    sm[4096+t]=0.1f*s; }
  for (int t=tid;t<4096;t+=256){ int l=t>>6,c=t&63; float s=0.f;   // x0 [0,4096)
    #pragma unroll
    for(int j=0;j<8;++j) s+=sm[8192+j*64+c]*sm[8704+l*8+j];
    sm[t]=0.1f*s; }
  __syncthreads();
  for (int t=tid;t<1024;t+=256){ int c=t&63; float yv=sm[4096+t]; float s=0.f;  // M0K [5120,6144)
    for(int l=0;l<64;++l) s+=relu_f(sm[l*64+c]+yv);
    sm[5120+t]=s*(1.f/64.f); }
  float ssum=0.f, ssq=0.f;                       // channel c = tid&63 (stride 256 preserves it)
  for (int t=tid;t<4096;t+=256){ int c=t&63; float xv=sm[t]; float s=0.f;
    #pragma unroll
    for(int k=0;k<16;++k){ float v=relu_f(xv+sm[4096+k*64+c]); s+=v; ssq+=v*v; }
    ssum+=s;
    ws[OFF_X1+(size_t)b*4096+t]=s*(1.f/16.f); }  // M0L
  __syncthreads();
  sm[6144+tid]=ssum; sm[6400+tid]=ssq;
  __syncthreads();
  if (tid<64){
    float ts =sm[6144+tid]+sm[6208+tid]+sm[6272+tid]+sm[6336+tid];
    float tss=sm[6400+tid]+sm[6464+tid]+sm[6528+tid]+sm[6592+tid];
    int stripe = b & (NSTRIPE-1);
    atomicAdd(&ws[OFF_SUM0+stripe*64+tid], ts);
    atomicAdd(&ws[OFF_SSQ0+stripe*64+tid], tss);
  }
  for (int t=tid;t<512;t+=256)  ws[OFF_HBL+(size_t)b*512+t]=sm[8704+t];
  for (int t=tid;t<128;t+=256)  ws[OFF_HBK+(size_t)b*128+t]=sm[9216+t];
  for (int t=tid;t<1024;t+=256) ws[OFF_Y0+(size_t)b*1024+t]=sm[4096+t];
  for (int t=tid;t<1024;t+=256) ws[OFF_Y1+(size_t)b*1024+t]=sm[5120+t];   // M0K
}

// K2: finalize BN -> s,t.
__global__ void k_bn(float* __restrict__ ws, const float* __restrict__ g_,
                     const float* __restrict__ b_, unsigned sumOff, unsigned outOff){
  int tid = threadIdx.x;
  if (tid < 64){
    float s=0.f, ss=0.f;
    for (int i=0;i<NSTRIPE;++i){ s+=ws[sumOff+i*64+tid]; ss+=ws[sumOff+1024+i*64+tid]; }
    const float invN = 1.0f/((float)BRR*LLL*KKK);
    float mu=s*invN, var=ss*invN-mu*mu;
    float sc = g_[tid]/sqrtf(var+BN_EPS);
    ws[outOff+tid]=sc;
    ws[outOff+64+tid]=b_[tid]-mu*sc;
  }
}

// K3: X1/Y1 in place over M0L/M0K.
__global__ __launch_bounds__(256) void k_xy1(float* __restrict__ ws,
                                             const float* __restrict__ P21,
                                             const float* __restrict__ P41){
  __shared__ float wt[4096], p41[512], mrow[1024], hbs[128], s0l[64], t0l[64];
  int bx = blockIdx.x, tid = threadIdx.x;
  for (int t=tid;t<4096;t+=256) wt[t] = 2.0f*P21[(t&63)*64 + (t>>6)];  // [c*64+o]
  for (int t=tid;t<512;t+=256)  p41[t] = P41[t];                        // [o*8+j]
  if (tid<64){ s0l[tid]=ws[OFF_S0+tid]; t0l[tid]=ws[OFF_T0+tid]; }
  bool isX = bx < 2048;
  int row0 = isX ? bx*16 : (bx-2048)*16;
  if (isX){
    for (int t=tid;t<1024;t+=256) mrow[t] = ws[OFF_X1+(size_t)row0*64+t];
    if (tid<128) hbs[tid] = ws[OFF_HBL+(size_t)row0*8+tid];
  } else {
    for (int t=tid;t<1024;t+=256) mrow[t] = ws[OFF_Y1+(size_t)row0*64+t];
    if (tid<128) hbs[tid] = ws[OFF_HBK+(size_t)row0*8+tid];
  }
  __syncthreads();
  for (int t=tid;t<1024;t+=256){ int c=t&63; mrow[t]=s0l[c]*mrow[t]+t0l[c]; }
  __syncthreads();
  int r4 = tid>>6, o = tid&63;
  #pragma unroll
  for (int rr=0;rr<4;++rr){
    int rl = rr*4 + r4;
    float s=0.f;
    for (int c=0;c<64;++c) s += wt[c*64+o]*mrow[rl*64+c];
    float s2=0.f;
    #pragma unroll
    for (int j=0;j<8;++j) s2 += p41[o*8+j]*hbs[rl*8+j];
    float res = s + 0.1f*s2;
    if (isX) ws[OFF_X1+(size_t)(row0+rl)*64+o] = res;
    else     ws[OFF_Y1+(size_t)(row0+rl)*64+o] = res;
  }
}

// ---- T1 tile LDS map (shared by k_pass1 loop body and k_final's t1_tile) ----
#define T_W1   0
#define T_X08  4384
#define T_Y0   4896
#define T_X1   5984
#define T_Y1   6496
#define T_S0   7520
#define T_T0   7584
#define T_P4T0 7648
#define T_HB8  8160
#define T_END  8224

// NOTE: c4 loop is unroll-4 (NOT full): full x16 unroll inflated the live-range
// window to VGPR=256 -> 2 waves/SIMD occupancy tier. unroll 4 keeps ILP while
// letting the allocator land below the tier boundary.
__device__ void t1_tile(float* sm, const float* __restrict__ ws,
                        const float* __restrict__ P11, const float* __restrict__ P40,
                        int b, int pblk, int tid,
                        float acc[8][4], int og, int pg, int lloc, int c0){
  for (int t=tid;t<4096;t+=256){ int o=t>>6,c=t&63; sm[T_W1+lds_row(o)+c]=2.0f*P11[t]; }
  for (int t=tid;t<1024;t+=256){ int k=t>>6,c=t&63; sm[T_Y0+k*68+c]=ws[OFF_Y0+(size_t)b*1024+t]; }
  for (int t=tid;t<512;t+=256)  sm[T_X1+t]=ws[OFF_X1+((size_t)b*64+pblk*8)*64+t];
  for (int t=tid;t<1024;t+=256) sm[T_Y1+t]=ws[OFF_Y1+(size_t)b*1024+t];
  for (int t=tid;t<512;t+=256){ int c=t&63,j=t>>6; sm[T_P4T0+j*64+c]=P40[c*8+j]; }
  if (tid<64){ sm[T_S0+tid]=ws[OFF_S0+tid]; sm[T_T0+tid]=ws[OFF_T0+tid]; }
  else if (tid<128){ int t2=tid-64; sm[T_HB8+t2]=ws[OFF_HBL+((size_t)b*64+pblk*8)*8+t2]; }
  __syncthreads();
  for (int e=tid;e<512;e+=256){ int l=e>>6,c=e&63; float s=0.f;
    #pragma unroll
    for(int j=0;j<8;++j) s += sm[T_P4T0+j*64+c]*sm[T_HB8+l*8+j];
    sm[T_X08+e]=0.1f*s; }
  __syncthreads();
  {
    float xb[8];
    *(float4*)&xb[0] = *(const float4*)&sm[T_X1 + lloc*64 + c0];
    *(float4*)&xb[4] = *(const float4*)&sm[T_X1 + lloc*64 + c0 + 4];
    #pragma unroll
    for (int i=0;i<4;++i){
      int k=(pg&3)*4+i;
      float yb[8];
      *(float4*)&yb[0] = *(const float4*)&sm[T_Y1 + k*64 + c0];
      *(float4*)&yb[4] = *(const float4*)&sm[T_Y1 + k*64 + c0 + 4];
      #pragma unroll
      for (int j=0;j<8;++j) acc[j][i]=xb[j]+yb[j];
    }
  }
  #pragma unroll 4
  for (int c4=0;c4<16;++c4){
    float4 xr  = *(const float4*)&sm[T_X08 + lloc*64 + c4*4];
    float4 s0v = *(const float4*)&sm[T_S0 + c4*4];
    float4 t0v = *(const float4*)&sm[T_T0 + c4*4];
    float4 aa[4];
    #pragma unroll
    for (int i=0;i<4;++i){
      int k=(pg&3)*4+i;
      float4 yr = *(const float4*)&sm[T_Y0 + k*68 + c4*4];
      aa[i].x = s0v.x*relu_f(xr.x+yr.x)+t0v.x;
      aa[i].y = s0v.y*relu_f(xr.y+yr.y)+t0v.y;
      aa[i].z = s0v.z*relu_f(xr.z+yr.z)+t0v.z;
      aa[i].w = s0v.w*relu_f(xr.w+yr.w)+t0v.w;
    }
    #pragma unroll
    for (int j=0;j<8;++j){
      float4 w = *(const float4*)&sm[T_W1 + lds_row(c0+j) + c4*4];
      #pragma unroll
      for (int i=0;i<4;++i)
        acc[j][i] += w.x*aa[i].x + w.y*aa[i].y + w.z*aa[i].z + w.w*aa[i].w;
    }
  }
  #pragma unroll
  for (int j=0;j<8;++j)
    #pragma unroll
    for (int i=0;i<4;++i) acc[j][i] = relu_f(acc[j][i]);
}

// K4: ONE block per b, looping all 8 pblk slices. M1K partials accumulate in
// LDS via per-iteration owner-writes (stride-33 layout: bank=(og*4+kg) mod 32
// -> all 32 banks, conflict-free RMW, zero atomics). This frees the 32
// persistent mk[][] VGPRs that were live through the hot loop.
#define MK_OFF 8224   // 4 wave-partials, 1088 floats each: [8224,12576)
__global__ __launch_bounds__(256) void k_pass1(float* __restrict__ ws,
                                               const float* __restrict__ P11,
                                               const float* __restrict__ P40){
  __shared__ float sm[12576];
  int b=blockIdx.x, tid=threadIdx.x;
  int og=tid&7, pg=tid>>3, lloc=pg>>2, kg=pg&3, c0=og*8, wv=tid>>6;
  // invariant staging (once per b)
  for (int t=tid;t<4096;t+=256){ int o=t>>6,c=t&63; sm[T_W1+lds_row(o)+c]=2.0f*P11[t]; }
  for (int t=tid;t<1024;t+=256){ int k=t>>6,c=t&63; sm[T_Y0+k*68+c]=ws[OFF_Y0+(size_t)b*1024+t]; }
  for (int t=tid;t<1024;t+=256) sm[T_Y1+t]=ws[OFF_Y1+(size_t)b*1024+t];
  for (int t=tid;t<512;t+=256){ int c=t&63,j=t>>6; sm[T_P4T0+j*64+c]=P40[c*8+j]; }
  if (tid<64){ sm[T_S0+tid]=ws[OFF_S0+tid]; sm[T_T0+tid]=ws[OFF_T0+tid]; }
  for (int t=tid;t<4352;t+=256) sm[MK_OFF+t]=0.f;
  float qsum[8];
  #pragma unroll
  for (int j=0;j<8;++j) qsum[j]=0.f;
  #pragma unroll 1
  for (int pblk=0;pblk<8;++pblk){
    __syncthreads();   // prev iter's X1/X08 reads done (and initial staging/MK zero)
    for (int t=tid;t<512;t+=256) sm[T_X1+t]=ws[OFF_X1+((size_t)b*64+pblk*8)*64+t];
    if (tid<64) sm[T_HB8+tid]=ws[OFF_HBL+((size_t)b*64+pblk*8)*8+tid];
    __syncthreads();
    for (int e=tid;e<512;e+=256){ int l=e>>6,c=e&63; float s=0.f;
      #pragma unroll
      for(int j=0;j<8;++j) s += sm[T_P4T0+j*64+c]*sm[T_HB8+l*8+j];
      sm[T_X08+e]=0.1f*s; }
    __syncthreads();
    float acc[8][4];
    {
      float xb[8];
      *(float4*)&xb[0] = *(const float4*)&sm[T_X1 + lloc*64 + c0];
      *(float4*)&xb[4] = *(const float4*)&sm[T_X1 + lloc*64 + c0 + 4];
      #pragma unroll
      for (int i=0;i<4;++i){
        int k=kg*4+i;
        float yb[8];
        *(float4*)&yb[0] = *(const float4*)&sm[T_Y1 + k*64 + c0];
        *(float4*)&yb[4] = *(const float4*)&sm[T_Y1 + k*64 + c0 + 4];
        #pragma unroll
        for (int j=0;j<8;++j) acc[j][i]=xb[j]+yb[j];
      }
    }
    #pragma unroll 4
    for (int c4=0;c4<16;++c4){
      float4 xr  = *(const float4*)&sm[T_X08 + lloc*64 + c4*4];
      float4 s0v = *(const float4*)&sm[T_S0 + c4*4];
      float4 t0v = *(const float4*)&sm[T_T0 + c4*4];
      float4 aa[4];
      #pragma unroll
      for (int i=0;i<4;++i){
        int k=kg*4+i;
        float4 yr = *(const float4*)&sm[T_Y0 + k*68 + c4*4];
        aa[i].x = s0v.x*relu_f(xr.x+yr.x)+t0v.x;
        aa[i].y = s0v.y*relu_f(xr.y+yr.y)+t0v.y;
        aa[i].z = s0v.z*relu_f(xr.z+yr.z)+t0v.z;
        aa[i].w = s0v.w*relu_f(xr.w+yr.w)+t0v.w;
      }
      #pragma unroll
      for (int j=0;j<8;++j){
        float4 w = *(const float4*)&sm[T_W1 + lds_row(c0+j) + c4*4];
        #pragma unroll
        for (int i=0;i<4;++i)
          acc[j][i] += w.x*aa[i].x + w.y*aa[i].y + w.z*aa[i].z + w.w*aa[i].w;
      }
    }
    #pragma unroll
    for (int j=0;j<8;++j)
      #pragma unroll
      for (int i=0;i<4;++i) acc[j][i] = relu_f(acc[j][i]);
    // ---- stats: ssq in regs; row-sums feed M1L ----
    float sj[8];
    #pragma unroll
    for (int j=0;j<8;++j){
      sj[j]=acc[j][0]+acc[j][1]+acc[j][2]+acc[j][3];
      qsum[j]+=acc[j][0]*acc[j][0]+acc[j][1]*acc[j][1]+acc[j][2]*acc[j][2]+acc[j][3]*acc[j][3];
    }
    // M1L: k-reduce over kg (tid bits 3,4), write by kg==0 lanes
    #pragma unroll
    for (int j=0;j<8;++j){
      float r=sj[j];
      r += __shfl_xor(r, 8, 64);
      r += __shfl_xor(r, 16, 64);
      sj[j]=r;
    }
    if (kg==0){
      const float inv16 = 1.f/16.f;
      float4 v0 = make_float4(sj[0]*inv16, sj[1]*inv16, sj[2]*inv16, sj[3]*inv16);
      float4 v1 = make_float4(sj[4]*inv16, sj[5]*inv16, sj[6]*inv16, sj[7]*inv16);
      size_t base = OFF_M1L + ((size_t)b*64 + pblk*8 + lloc)*64 + c0;
      *(float4*)&ws[base]   = v0;
      *(float4*)&ws[base+4] = v1;
    }
    // M1K partial: lloc-pair sum via shfl (tid bit5 = lloc bit0), owner += in LDS
    #pragma unroll
    for (int j=0;j<8;++j){
      #pragma unroll
      for (int i=0;i<4;++i){
        float v = acc[j][i] + __shfl_xor(acc[j][i], 32, 64);
        if ((tid & 32)==0)
          sm[MK_OFF + wv*1088 + (og*4+kg)*33 + i*8 + j] += v;
      }
    }
  }
  __syncthreads();
  // M1K finalize (plain store) + BN1 channel sum from the same accumulator
  float tsacc=0.f;
  #pragma unroll
  for (int r=0;r<4;++r){
    int e = tid + r*256;
    int k=e>>6, c=e&63;
    int a = ((c>>3)*4+(k>>2))*33 + (k&3)*8 + (c&7);
    float v = sm[MK_OFF+a]+sm[MK_OFF+1088+a]+sm[MK_OFF+2176+a]+sm[MK_OFF+3264+a];
    tsacc += v;
    ws[OFF_M1K+(size_t)b*1024+e] = v*(1.f/64.f);
  }
  __syncthreads();   // mk reads done -> overlay stats
  sm[8224 + (tid&63)*5 + wv] = tsacc;
  #pragma unroll
  for (int j=0;j<8;++j) sm[8544+(c0+j)*33+pg] = qsum[j];
  __syncthreads();
  if (tid<64){
    float ts  = sm[8224+tid*5+0]+sm[8224+tid*5+1]+sm[8224+tid*5+2]+sm[8224+tid*5+3];
    float tss = 0.f;
    for (int g=0; g<32; ++g) tss += sm[8544+tid*33+g];
    int stripe = b & (NSTRIPE-1);
    atomicAdd(&ws[OFF_SUM1+stripe*64+tid], ts);
    atomicAdd(&ws[OFF_SSQ1+stripe*64+tid], tss);
  }
}

// K5: tiny per-b pass: X2/Y2 from raw M1L/M1K + BN1 affine. No atomics.
__global__ __launch_bounds__(256) void k_xy2s(float* __restrict__ ws,
                                              const float* __restrict__ P22,
                                              const float* __restrict__ P42){
  __shared__ float mln[4352];   // [l][68] : s1*M1L+t1
  __shared__ float mkn[1088];   // [k][68] : s1*M1K+t1
  __shared__ float w2[512];     // [c*8+o2] = 2*P22[o2][c]
  __shared__ float p42s[64];    // [o2*8+j]
  __shared__ float hbl[512];    // [l*8+j]
  __shared__ float hbk[128];    // [k*8+j]
  __shared__ float s1l[64], t1l[64];
  int b = blockIdx.x, tid = threadIdx.x;
  if (tid<64){ s1l[tid]=ws[OFF_S1+tid]; t1l[tid]=ws[OFF_T1+tid]; }
  for (int t=tid;t<512;t+=256) w2[t] = 2.0f*P22[(t&7)*64 + (t>>3)];
  if (tid<64) p42s[tid] = P42[tid];
  for (int t=tid;t<512;t+=256) hbl[t] = ws[OFF_HBL+(size_t)b*512+t];
  if (tid<128) hbk[tid] = ws[OFF_HBK+(size_t)b*128+tid];
  __syncthreads();
  for (int t=tid;t<4096;t+=256){ int l=t>>6,c=t&63;
    mln[l*68+c] = s1l[c]*ws[OFF_M1L+(size_t)b*4096+t] + t1l[c]; }
  for (int t=tid;t<1024;t+=256){ int k=t>>6,c=t&63;
    mkn[k*68+c] = s1l[c]*ws[OFF_M1K+(size_t)b*1024+t] + t1l[c]; }
  __syncthreads();
  for (int t=tid;t<512;t+=256){
    int l=t>>3, o2=t&7;
    float s=0.f;
    for (int c=0;c<64;++c) s += w2[c*8+o2]*mln[l*68+c];
    float s2=0.f;
    #pragma unroll
    for (int j=0;j<8;++j) s2 += p42s[o2*8+j]*hbl[l*8+j];
    ws[OFF_X2+(size_t)b*512+t] = s + 0.1f*s2;
  }
  if (tid<128){
    int k=tid>>3, o2=tid&7;
    float s=0.f;
    for (int c=0;c<64;++c) s += w2[c*8+o2]*mkn[k*68+c];
    float s2=0.f;
    #pragma unroll
    for (int j=0;j<8;++j) s2 += p42s[o2*8+j]*hbk[k*8+j];
    ws[OFF_Y2+(size_t)b*128+tid] = s + 0.1f*s2;
  }
}

// K6: tile pass + layer-2 + normalize + output.
// T1c layout now c*133 + (c>>3) + p: the +og stagger turns the 8-way write
// conflict (bank = 8og+...) into a 2-way (bank = 9og+..., free); reads keep
// wave-uniform offset -> still conflict-free.
__global__ __launch_bounds__(256) void k_final(const float* __restrict__ ws,
                                               const float* __restrict__ P11,
                                               const float* __restrict__ P40,
                                               const float* __restrict__ P12,
                                               float* __restrict__ out,
                                               long long out_cap, int interleaved){
  __shared__ float sm[9156];   // T1c [0,8514); W2l [8516,9028); s1 [9028); t1 [9092)
  int bid=blockIdx.x, b=bid>>3, pblk=bid&7, tid=threadIdx.x;
  int og=tid&7, pg=tid>>3, lloc=pg>>2, c0=og*8;
  for (int t=tid;t<512;t+=256) sm[8516+t] = 2.0f*P12[t];   // [o2*64+c]
  if (tid<64) sm[9028+tid]=ws[OFF_S1+tid];
  else if (tid<128) sm[9092+(tid-64)]=ws[OFF_T1+(tid-64)];
  float acc[8][4];
  t1_tile(sm, ws, P11, P40, b, pblk, tid, acc, og, pg, lloc, c0);
  __syncthreads();
  {
    int kg = pg&3;
    #pragma unroll
    for (int i=0;i<4;++i){
      int p = lloc*16 + kg*4 + i;
      #pragma unroll
      for (int j=0;j<8;++j) sm[(c0+j)*133 + og + p] = acc[j][i];  // T1c staggered
    }
  }
  __syncthreads();
  if (tid < 128){
    int p = tid, k = p & 15, lglob = pblk*8 + (p>>4);
    float a2[8];
    {
      const float* xp = ws + OFF_X2 + ((size_t)b*64+lglob)*8;
      const float* yp = ws + OFF_Y2 + ((size_t)b*16+k)*8;
      float4 x0_ = *(const float4*)&xp[0];
      float4 x1_ = *(const float4*)&xp[4];
      float4 y0_ = *(const float4*)&yp[0];
      float4 y1_ = *(const float4*)&yp[4];
      a2[0]=x0_.x+y0_.x; a2[1]=x0_.y+y0_.y; a2[2]=x0_.z+y0_.z; a2[3]=x0_.w+y0_.w;
      a2[4]=x1_.x+y1_.x; a2[5]=x1_.y+y1_.y; a2[6]=x1_.z+y1_.z; a2[7]=x1_.w+y1_.w;
    }
    for (int c=0;c<64;++c){
      float tn = sm[9028+c]*sm[c*133 + (c>>3) + p] + sm[9092+c];   // s1*T1+t1
      #pragma unroll
      for (int o2=0;o2<8;++o2) a2[o2] += sm[8516+o2*64+c]*tn;
    }
    float nrm=0.f;
    #pragma unroll
    for (int o2=0;o2<8;++o2) nrm += a2[o2]*a2[o2];
    float inv = 1.0f/sqrtf(nrm);
    size_t pos = (size_t)b*PPP + lglob*KKK + k;
    if (interleaved){
      long long idx = (long long)pos*8;
      if (idx+8 <= out_cap){
        *(float4*)&out[idx]   = make_float4(a2[0]*inv, a2[4]*inv, a2[1]*inv, a2[5]*inv);
        *(float4*)&out[idx+4] = make_float4(a2[2]*inv, a2[6]*inv, a2[3]*inv, a2[7]*inv);
      }
    } else {
      long long idx = (long long)pos*4;
      if (idx+4 <= out_cap)
        *(float4*)&out[idx] = make_float4(a2[0]*inv, a2[1]*inv, a2[2]*inv, a2[3]*inv);
    }
  }
}

extern "C" void kernel_launch(void* const* d_in, const int* in_sizes, int n_in,
                              void* d_out, int out_size, void* d_ws, size_t ws_size,
                              hipStream_t stream) {
  if (n_in < 15) return;
  if (in_sizes[0] != BRR*4096 || in_sizes[1] != BRR*4096) return;
  if (in_sizes[4] != 512)  return;   // P4_0 (64,8)
  if (in_sizes[7] != 4096) return;   // P1_1 (64,64)
  if (in_sizes[12] != 512) return;   // P1_2 (8,64)
  if (ws_size < (size_t)WS_FLOATS*4) return;   // clean fail, not a fault

  const float* Hr   = (const float*)d_in[0];
  const float* Hi   = (const float*)d_in[1];
  const float* P4_0 = (const float*)d_in[4];
  const float* g0   = (const float*)d_in[5];
  const float* b0   = (const float*)d_in[6];
  const float* P1_1 = (const float*)d_in[7];
  const float* P2_1 = (const float*)d_in[8];
  const float* P4_1 = (const float*)d_in[9];
  const float* g1   = (const float*)d_in[10];
  const float* b1   = (const float*)d_in[11];
  const float* P1_2 = (const float*)d_in[12];
  const float* P2_2 = (const float*)d_in[13];
  const float* P4_2 = (const float*)d_in[14];
  float* ws  = (float*)d_ws;
  float* out = (float*)d_out;
  int interleaved = (out_size >= 4194304) ? 1 : 0;

  k_zero<<<4, 256, 0, stream>>>((float4*)(ws + OFF_SUM0), 4096/4);
  k_prep<<<BRR, 256, 0, stream>>>(Hr, Hi, P4_0, ws);
  k_bn<<<1, 64, 0, stream>>>(ws, g0, b0, OFF_SUM0, OFF_S0);
  k_xy1<<<2560, 256, 0, stream>>>(ws, P2_1, P4_1);
  k_pass1<<<BRR, 256, 0, stream>>>(ws, P1_1, P4_0);
  k_bn<<<1, 64, 0, stream>>>(ws, g1, b1, OFF_SUM1, OFF_S1);
  k_xy2s<<<BRR, 256, 0, stream>>>(ws, P2_2, P4_2);
  k_final<<<BRR*8, 256, 0, stream>>>(ws, P1_1, P4_0, P1_2, out,
                                     (long long)out_size, interleaved);
}

// Round 5
// 381.497 us; speedup vs baseline: 6.7296x; 1.0500x over previous
//
#include <hip/hip_runtime.h>
#include <math.h>

#define BRR 512
#define LLL 64
#define KKK 16
#define EEE 64
#define CC2 8
#define PPP 1024
#define BN_EPS 1e-5f
#define NSTRIPE 16

__device__ __forceinline__ float relu_f(float v){ return v>0.f?v:0.f; }
// Row-padded W1 layout: stride 68 + 4-float stagger per 8-row octet.
__device__ __forceinline__ int lds_row(int r){ return r*68 + (((r>>3)&7)<<2); }

// ---- d_ws float layout ----
#define OFF_HBL  0u          // [(b*64+l)*8+c2]            262144
#define OFF_HBK  262144u     // [(b*16+k)*8+c2]             65536
#define OFF_Y0   327680u     // [b*1024 + k*64+c]          524288
#define OFF_X1   851968u     // [(b*64+l)*64+c] M0L->X1   2097152
#define OFF_Y1   2949120u    // [b*1024 + k*64+o] M0K->Y1  524288
#define OFF_X2   3473408u    // [(b*64+l)*8+o2]            262144
#define OFF_Y2   3735552u    // [(b*16+k)*8+o2]             65536
#define OFF_M1L  3801088u    // [b*4096 + l*64+c] raw k-mean of T1   2097152
#define OFF_M1K  5898240u    // [b*1024 + k*64+c] raw l-mean half0   524288
#define OFF_SUM0 6422528u
#define OFF_SSQ0 6423552u
#define OFF_SUM1 6424576u
#define OFF_SSQ1 6425600u
#define OFF_S0   6426624u
#define OFF_T0   6426688u
#define OFF_S1   6426752u
#define OFF_T1   6426816u
#define WS_FLOATS 6426880u   // 25,707,520 bytes (small/fallback footprint)
// ---- big-ws extension (only touched when ws_size >= WS_BIG*4) ----
#define OFF_M1KB 6426880u    // M1K half1 partial                    524288
#define OFF_T1S  6951168u    // raw T1 tiles [(b*8+pblk)*8192 + j*1024 + lane*4 + i]
#define WS_BIG   40505600u   // 162,022,400 bytes (~154.5 MiB)

// ---------------------------------------------------------------------------
// K0: zero stat accumulators only (4096 floats).
__global__ void k_zero(float4* __restrict__ p, int n4){
  int t = blockIdx.x*256 + threadIdx.x;
  if (t < n4) p[t] = make_float4(0.f,0.f,0.f,0.f);
}

// K1: per-b prep. HbL,HbK,y0,M0K,M0L + BN0 channel sums. All inputs f32.
__global__ __launch_bounds__(256) void k_prep(const float* __restrict__ Hr,
                                              const float* __restrict__ Hi,
                                              const float* __restrict__ P40,
                                              float* __restrict__ ws){
  __shared__ float sm[9344];
  int b = blockIdx.x, tid = threadIdx.x;
  const float* hrg = Hr + (size_t)b*4096;
  const float* hig = Hi + (size_t)b*4096;
  for (int t=tid;t<4096;t+=256){ sm[t]=hrg[t]; sm[4096+t]=hig[t]; }
  for (int t=tid;t<512;t+=256){ int c=t&63,j=t>>6; sm[8192+j*64+c]=P40[c*8+j]; }
  __syncthreads();
  for (int t=tid;t<512;t+=256){ int l=t>>3,c2=t&7;          // HbL [8704,9216)
    const float* src=sm+((c2<4)?0:4096); int u=c2&3;
    float s=0.f;
    #pragma unroll
    for(int k=0;k<16;++k) s+=src[(l*16+k)*4+u];
    sm[8704+t]=s*(1.f/16.f); }
  for (int t=tid;t<128;t+=256){ int k=t>>3,c2=t&7;          // HbK [9216,9344)
    const float* src=sm+((c2<4)?0:4096); int u=c2&3;
    float s=0.f;
    for(int l=0;l<64;++l) s+=src[(l*16+k)*4+u];
    sm[9216+t]=s*(1.f/64.f); }
  __syncthreads();
  for (int t=tid;t<1024;t+=256){ int k=t>>6,c=t&63; float s=0.f;   // y0 [4096,5120)
    #pragma unroll
    for(int j=0;j<8;++j) s+=sm[8192+j*64+c]*sm[9216+k*8+j];
    sm[4096+t]=0.1f*s; }
  for (int t=tid;t<4096;t+=256){ int l=t>>6,c=t&63; float s=0.f;   // x0 [0,4096)
    #pragma unroll
    for(int j=0;j<8;++j) s+=sm[8192+j*64+c]*sm[8704+l*8+j];
    sm[t]=0.1f*s; }
  __syncthreads();
  for (int t=tid;t<1024;t+=256){ int c=t&63; float yv=sm[4096+t]; float s=0.f;  // M0K [5120,6144)
    for(int l=0;l<64;++l) s+=relu_f(sm[l*64+c]+yv);
    sm[5120+t]=s*(1.f/64.f); }
  float ssum=0.f, ssq=0.f;                       // channel c = tid&63 (stride 256 preserves it)
  for (int t=tid;t<4096;t+=256){ int c=t&63; float xv=sm[t]; float s=0.f;
    #pragma unroll
    for(int k=0;k<16;++k){ float v=relu_f(xv+sm[4096+k*64+c]); s+=v; ssq+=v*v; }
    ssum+=s;
    ws[OFF_X1+(size_t)b*4096+t]=s*(1.f/16.f); }  // M0L
  __syncthreads();
  sm[6144+tid]=ssum; sm[6400+tid]=ssq;
  __syncthreads();
  if (tid<64){
    float ts =sm[6144+tid]+sm[6208+tid]+sm[6272+tid]+sm[6336+tid];
    float tss=sm[6400+tid]+sm[6464+tid]+sm[6528+tid]+sm[6592+tid];
    int stripe = b & (NSTRIPE-1);
    atomicAdd(&ws[OFF_SUM0+stripe*64+tid], ts);
    atomicAdd(&ws[OFF_SSQ0+stripe*64+tid], tss);
  }
  for (int t=tid;t<512;t+=256)  ws[OFF_HBL+(size_t)b*512+t]=sm[8704+t];
  for (int t=tid;t<128;t+=256)  ws[OFF_HBK+(size_t)b*128+t]=sm[9216+t];
  for (int t=tid;t<1024;t+=256) ws[OFF_Y0+(size_t)b*1024+t]=sm[4096+t];
  for (int t=tid;t<1024;t+=256) ws[OFF_Y1+(size_t)b*1024+t]=sm[5120+t];   // M0K
}

// K2: finalize BN -> s,t.
__global__ void k_bn(float* __restrict__ ws, const float* __restrict__ g_,
                     const float* __restrict__ b_, unsigned sumOff, unsigned outOff){
  int tid = threadIdx.x;
  if (tid < 64){
    float s=0.f, ss=0.f;
    for (int i=0;i<NSTRIPE;++i){ s+=ws[sumOff+i*64+tid]; ss+=ws[sumOff+1024+i*64+tid]; }
    const float invN = 1.0f/((float)BRR*LLL*KKK);
    float mu=s*invN, var=ss*invN-mu*mu;
    float sc = g_[tid]/sqrtf(var+BN_EPS);
    ws[outOff+tid]=sc;
    ws[outOff+64+tid]=b_[tid]-mu*sc;
  }
}

// K3: X1/Y1 in place over M0L/M0K.
__global__ __launch_bounds__(256) void k_xy1(float* __restrict__ ws,
                                             const float* __restrict__ P21,
                                             const float* __restrict__ P41){
  __shared__ float wt[4096], p41[512], mrow[1024], hbs[128], s0l[64], t0l[64];
  int bx = blockIdx.x, tid = threadIdx.x;
  for (int t=tid;t<4096;t+=256) wt[t] = 2.0f*P21[(t&63)*64 + (t>>6)];  // [c*64+o]
  for (int t=tid;t<512;t+=256)  p41[t] = P41[t];                        // [o*8+j]
  if (tid<64){ s0l[tid]=ws[OFF_S0+tid]; t0l[tid]=ws[OFF_T0+tid]; }
  bool isX = bx < 2048;
  int row0 = isX ? bx*16 : (bx-2048)*16;
  if (isX){
    for (int t=tid;t<1024;t+=256) mrow[t] = ws[OFF_X1+(size_t)row0*64+t];
    if (tid<128) hbs[tid] = ws[OFF_HBL+(size_t)row0*8+tid];
  } else {
    for (int t=tid;t<1024;t+=256) mrow[t] = ws[OFF_Y1+(size_t)row0*64+t];
    if (tid<128) hbs[tid] = ws[OFF_HBK+(size_t)row0*8+tid];
  }
  __syncthreads();
  for (int t=tid;t<1024;t+=256){ int c=t&63; mrow[t]=s0l[c]*mrow[t]+t0l[c]; }
  __syncthreads();
  int r4 = tid>>6, o = tid&63;
  #pragma unroll
  for (int rr=0;rr<4;++rr){
    int rl = rr*4 + r4;
    float s=0.f;
    for (int c=0;c<64;++c) s += wt[c*64+o]*mrow[rl*64+c];
    float s2=0.f;
    #pragma unroll
    for (int j=0;j<8;++j) s2 += p41[o*8+j]*hbs[rl*8+j];
    float res = s + 0.1f*s2;
    if (isX) ws[OFF_X1+(size_t)(row0+rl)*64+o] = res;
    else     ws[OFF_Y1+(size_t)(row0+rl)*64+o] = res;
  }
}

// ---- T1 tile LDS map (shared by k_pass1 loop body and k_final's t1_tile) ----
#define T_W1   0
#define T_X08  4384
#define T_Y0   4896
#define T_X1   5984
#define T_Y1   6496
#define T_S0   7520
#define T_T0   7584
#define T_P4T0 7648
#define T_HB8  8160
#define T_END  8224

// NOTE: c4 loop is unroll-4 (NOT full): full x16 unroll inflated the live-range
// window to VGPR=256 -> 2 waves/SIMD occupancy tier. unroll 4 keeps ILP while
// letting the allocator land below the tier boundary (r4: VGPR=76).
__device__ void t1_tile(float* sm, const float* __restrict__ ws,
                        const float* __restrict__ P11, const float* __restrict__ P40,
                        int b, int pblk, int tid,
                        float acc[8][4], int og, int pg, int lloc, int c0){
  for (int t=tid;t<4096;t+=256){ int o=t>>6,c=t&63; sm[T_W1+lds_row(o)+c]=2.0f*P11[t]; }
  for (int t=tid;t<1024;t+=256){ int k=t>>6,c=t&63; sm[T_Y0+k*68+c]=ws[OFF_Y0+(size_t)b*1024+t]; }
  for (int t=tid;t<512;t+=256)  sm[T_X1+t]=ws[OFF_X1+((size_t)b*64+pblk*8)*64+t];
  for (int t=tid;t<1024;t+=256) sm[T_Y1+t]=ws[OFF_Y1+(size_t)b*1024+t];
  for (int t=tid;t<512;t+=256){ int c=t&63,j=t>>6; sm[T_P4T0+j*64+c]=P40[c*8+j]; }
  if (tid<64){ sm[T_S0+tid]=ws[OFF_S0+tid]; sm[T_T0+tid]=ws[OFF_T0+tid]; }
  else if (tid<128){ int t2=tid-64; sm[T_HB8+t2]=ws[OFF_HBL+((size_t)b*64+pblk*8)*8+t2]; }
  __syncthreads();
  for (int e=tid;e<512;e+=256){ int l=e>>6,c=e&63; float s=0.f;
    #pragma unroll
    for(int j=0;j<8;++j) s += sm[T_P4T0+j*64+c]*sm[T_HB8+l*8+j];
    sm[T_X08+e]=0.1f*s; }
  __syncthreads();
  {
    float xb[8];
    *(float4*)&xb[0] = *(const float4*)&sm[T_X1 + lloc*64 + c0];
    *(float4*)&xb[4] = *(const float4*)&sm[T_X1 + lloc*64 + c0 + 4];
    #pragma unroll
    for (int i=0;i<4;++i){
      int k=(pg&3)*4+i;
      float yb[8];
      *(float4*)&yb[0] = *(const float4*)&sm[T_Y1 + k*64 + c0];
      *(float4*)&yb[4] = *(const float4*)&sm[T_Y1 + k*64 + c0 + 4];
      #pragma unroll
      for (int j=0;j<8;++j) acc[j][i]=xb[j]+yb[j];
    }
  }
  #pragma unroll 4
  for (int c4=0;c4<16;++c4){
    float4 xr  = *(const float4*)&sm[T_X08 + lloc*64 + c4*4];
    float4 s0v = *(const float4*)&sm[T_S0 + c4*4];
    float4 t0v = *(const float4*)&sm[T_T0 + c4*4];
    float4 aa[4];
    #pragma unroll
    for (int i=0;i<4;++i){
      int k=(pg&3)*4+i;
      float4 yr = *(const float4*)&sm[T_Y0 + k*68 + c4*4];
      aa[i].x = s0v.x*relu_f(xr.x+yr.x)+t0v.x;
      aa[i].y = s0v.y*relu_f(xr.y+yr.y)+t0v.y;
      aa[i].z = s0v.z*relu_f(xr.z+yr.z)+t0v.z;
      aa[i].w = s0v.w*relu_f(xr.w+yr.w)+t0v.w;
    }
    #pragma unroll
    for (int j=0;j<8;++j){
      float4 w = *(const float4*)&sm[T_W1 + lds_row(c0+j) + c4*4];
      #pragma unroll
      for (int i=0;i<4;++i)
        acc[j][i] += w.x*aa[i].x + w.y*aa[i].y + w.z*aa[i].z + w.w*aa[i].w;
    }
  }
  #pragma unroll
  for (int j=0;j<8;++j)
    #pragma unroll
    for (int i=0;i<4;++i) acc[j][i] = relu_f(acc[j][i]);
}

// K4: per-b (or per half-b when hshift=1) tile loop. M1K partials in LDS
// stride-33 owner cells (all-32-bank RMW, zero atomics). Optionally stores
// raw T1 tiles (coalesced float4, lane-consecutive) so k_final can stream
// them back instead of recomputing the GEMM.
#define MK_OFF 8224   // 4 wave-partials, 1088 floats each: [8224,12576)
__global__ __launch_bounds__(256) void k_pass1(float* __restrict__ ws,
                                               const float* __restrict__ P11,
                                               const float* __restrict__ P40,
                                               int hshift, int t1s){
  __shared__ float sm[12576];
  int nh = 1<<hshift;
  int b = blockIdx.x >> hshift, h = blockIdx.x & (nh-1);
  int pb0 = h*(8>>hshift), pb1 = pb0 + (8>>hshift);
  int tid=threadIdx.x;
  int og=tid&7, pg=tid>>3, lloc=pg>>2, kg=pg&3, c0=og*8, wv=tid>>6;
  // invariant staging (once per block)
  for (int t=tid;t<4096;t+=256){ int o=t>>6,c=t&63; sm[T_W1+lds_row(o)+c]=2.0f*P11[t]; }
  for (int t=tid;t<1024;t+=256){ int k=t>>6,c=t&63; sm[T_Y0+k*68+c]=ws[OFF_Y0+(size_t)b*1024+t]; }
  for (int t=tid;t<1024;t+=256) sm[T_Y1+t]=ws[OFF_Y1+(size_t)b*1024+t];
  for (int t=tid;t<512;t+=256){ int c=t&63,j=t>>6; sm[T_P4T0+j*64+c]=P40[c*8+j]; }
  if (tid<64){ sm[T_S0+tid]=ws[OFF_S0+tid]; sm[T_T0+tid]=ws[OFF_T0+tid]; }
  for (int t=tid;t<4352;t+=256) sm[MK_OFF+t]=0.f;
  float qsum[8];
  #pragma unroll
  for (int j=0;j<8;++j) qsum[j]=0.f;
  #pragma unroll 1
  for (int pblk=pb0;pblk<pb1;++pblk){
    __syncthreads();   // prev iter's X1/X08 reads done (and initial staging/MK zero)
    for (int t=tid;t<512;t+=256) sm[T_X1+t]=ws[OFF_X1+((size_t)b*64+pblk*8)*64+t];
    if (tid<64) sm[T_HB8+tid]=ws[OFF_HBL+((size_t)b*64+pblk*8)*8+tid];
    __syncthreads();
    for (int e=tid;e<512;e+=256){ int l=e>>6,c=e&63; float s=0.f;
      #pragma unroll
      for(int j=0;j<8;++j) s += sm[T_P4T0+j*64+c]*sm[T_HB8+l*8+j];
      sm[T_X08+e]=0.1f*s; }
    __syncthreads();
    float acc[8][4];
    {
      float xb[8];
      *(float4*)&xb[0] = *(const float4*)&sm[T_X1 + lloc*64 + c0];
      *(float4*)&xb[4] = *(const float4*)&sm[T_X1 + lloc*64 + c0 + 4];
      #pragma unroll
      for (int i=0;i<4;++i){
        int k=kg*4+i;
        float yb[8];
        *(float4*)&yb[0] = *(const float4*)&sm[T_Y1 + k*64 + c0];
        *(float4*)&yb[4] = *(const float4*)&sm[T_Y1 + k*64 + c0 + 4];
        #pragma unroll
        for (int j=0;j<8;++j) acc[j][i]=xb[j]+yb[j];
      }
    }
    #pragma unroll 4
    for (int c4=0;c4<16;++c4){
      float4 xr  = *(const float4*)&sm[T_X08 + lloc*64 + c4*4];
      float4 s0v = *(const float4*)&sm[T_S0 + c4*4];
      float4 t0v = *(const float4*)&sm[T_T0 + c4*4];
      float4 aa[4];
      #pragma unroll
      for (int i=0;i<4;++i){
        int k=kg*4+i;
        float4 yr = *(const float4*)&sm[T_Y0 + k*68 + c4*4];
        aa[i].x = s0v.x*relu_f(xr.x+yr.x)+t0v.x;
        aa[i].y = s0v.y*relu_f(xr.y+yr.y)+t0v.y;
        aa[i].z = s0v.z*relu_f(xr.z+yr.z)+t0v.z;
        aa[i].w = s0v.w*relu_f(xr.w+yr.w)+t0v.w;
      }
      #pragma unroll
      for (int j=0;j<8;++j){
        float4 w = *(const float4*)&sm[T_W1 + lds_row(c0+j) + c4*4];
        #pragma unroll
        for (int i=0;i<4;++i)
          acc[j][i] += w.x*aa[i].x + w.y*aa[i].y + w.z*aa[i].z + w.w*aa[i].w;
      }
    }
    #pragma unroll
    for (int j=0;j<8;++j)
      #pragma unroll
      for (int i=0;i<4;++i) acc[j][i] = relu_f(acc[j][i]);
    // ---- optional raw-T1 spill (coalesced: lane-consecutive float4) ----
    if (t1s){
      size_t base = OFF_T1S + ((size_t)b*8 + pblk)*8192 + (size_t)tid*4;
      #pragma unroll
      for (int j=0;j<8;++j)
        *(float4*)&ws[base + j*1024] =
          make_float4(acc[j][0],acc[j][1],acc[j][2],acc[j][3]);
    }
    // ---- stats: ssq in regs; row-sums feed M1L ----
    float sj[8];
    #pragma unroll
    for (int j=0;j<8;++j){
      sj[j]=acc[j][0]+acc[j][1]+acc[j][2]+acc[j][3];
      qsum[j]+=acc[j][0]*acc[j][0]+acc[j][1]*acc[j][1]+acc[j][2]*acc[j][2]+acc[j][3]*acc[j][3];
    }
    // M1L: k-reduce over kg (tid bits 3,4), write by kg==0 lanes
    #pragma unroll
    for (int j=0;j<8;++j){
      float r=sj[j];
      r += __shfl_xor(r, 8, 64);
      r += __shfl_xor(r, 16, 64);
      sj[j]=r;
    }
    if (kg==0){
      const float inv16 = 1.f/16.f;
      float4 v0 = make_float4(sj[0]*inv16, sj[1]*inv16, sj[2]*inv16, sj[3]*inv16);
      float4 v1 = make_float4(sj[4]*inv16, sj[5]*inv16, sj[6]*inv16, sj[7]*inv16);
      size_t base = OFF_M1L + ((size_t)b*64 + pblk*8 + lloc)*64 + c0;
      *(float4*)&ws[base]   = v0;
      *(float4*)&ws[base+4] = v1;
    }
    // M1K partial: lloc-pair sum via shfl (tid bit5 = lloc bit0), owner += in LDS
    #pragma unroll
    for (int j=0;j<8;++j){
      #pragma unroll
      for (int i=0;i<4;++i){
        float v = acc[j][i] + __shfl_xor(acc[j][i], 32, 64);
        if ((tid & 32)==0)
          sm[MK_OFF + wv*1088 + (og*4+kg)*33 + i*8 + j] += v;
      }
    }
  }
  __syncthreads();
  // M1K finalize (plain store to this half's region) + BN1 channel sum
  unsigned mko = h ? OFF_M1KB : OFF_M1K;
  float tsacc=0.f;
  #pragma unroll
  for (int r=0;r<4;++r){
    int e = tid + r*256;
    int k=e>>6, c=e&63;
    int a = ((c>>3)*4+(k>>2))*33 + (k&3)*8 + (c&7);
    float v = sm[MK_OFF+a]+sm[MK_OFF+1088+a]+sm[MK_OFF+2176+a]+sm[MK_OFF+3264+a];
    tsacc += v;
    ws[mko+(size_t)b*1024+e] = v*(1.f/64.f);
  }
  __syncthreads();   // mk reads done -> overlay stats
  sm[8224 + (tid&63)*5 + wv] = tsacc;
  #pragma unroll
  for (int j=0;j<8;++j) sm[8544+(c0+j)*33+pg] = qsum[j];
  __syncthreads();
  if (tid<64){
    float ts  = sm[8224+tid*5+0]+sm[8224+tid*5+1]+sm[8224+tid*5+2]+sm[8224+tid*5+3];
    float tss = 0.f;
    for (int g=0; g<32; ++g) tss += sm[8544+tid*33+g];
    int stripe = b & (NSTRIPE-1);
    atomicAdd(&ws[OFF_SUM1+stripe*64+tid], ts);
    atomicAdd(&ws[OFF_SSQ1+stripe*64+tid], tss);
  }
}

// K5: tiny per-b pass: X2/Y2 from raw M1L/M1K + BN1 affine. No atomics.
__global__ __launch_bounds__(256) void k_xy2s(float* __restrict__ ws,
                                              const float* __restrict__ P22,
                                              const float* __restrict__ P42,
                                              int two){
  __shared__ float mln[4352];   // [l][68] : s1*M1L+t1
  __shared__ float mkn[1088];   // [k][68] : s1*M1K+t1
  __shared__ float w2[512];     // [c*8+o2] = 2*P22[o2][c]
  __shared__ float p42s[64];    // [o2*8+j]
  __shared__ float hbl[512];    // [l*8+j]
  __shared__ float hbk[128];    // [k*8+j]
  __shared__ float s1l[64], t1l[64];
  int b = blockIdx.x, tid = threadIdx.x;
  if (tid<64){ s1l[tid]=ws[OFF_S1+tid]; t1l[tid]=ws[OFF_T1+tid]; }
  for (int t=tid;t<512;t+=256) w2[t] = 2.0f*P22[(t&7)*64 + (t>>3)];
  if (tid<64) p42s[tid] = P42[tid];
  for (int t=tid;t<512;t+=256) hbl[t] = ws[OFF_HBL+(size_t)b*512+t];
  if (tid<128) hbk[tid] = ws[OFF_HBK+(size_t)b*128+tid];
  __syncthreads();
  for (int t=tid;t<4096;t+=256){ int l=t>>6,c=t&63;
    mln[l*68+c] = s1l[c]*ws[OFF_M1L+(size_t)b*4096+t] + t1l[c]; }
  for (int t=tid;t<1024;t+=256){ int k=t>>6,c=t&63;
    float mv = ws[OFF_M1K+(size_t)b*1024+t];
    if (two) mv += ws[OFF_M1KB+(size_t)b*1024+t];
    mkn[k*68+c] = s1l[c]*mv + t1l[c]; }
  __syncthreads();
  for (int t=tid;t<512;t+=256){
    int l=t>>3, o2=t&7;
    float s=0.f;
    for (int c=0;c<64;++c) s += w2[c*8+o2]*mln[l*68+c];
    float s2=0.f;
    #pragma unroll
    for (int j=0;j<8;++j) s2 += p42s[o2*8+j]*hbl[l*8+j];
    ws[OFF_X2+(size_t)b*512+t] = s + 0.1f*s2;
  }
  if (tid<128){
    int k=tid>>3, o2=tid&7;
    float s=0.f;
    for (int c=0;c<64;++c) s += w2[c*8+o2]*mkn[k*68+c];
    float s2=0.f;
    #pragma unroll
    for (int j=0;j<8;++j) s2 += p42s[o2*8+j]*hbk[k*8+j];
    ws[OFF_Y2+(size_t)b*128+tid] = s + 0.1f*s2;
  }
}

// K6: layer-2 + normalize + output. t1s=1: stream the stored raw T1 tile
// (32 KB coalesced) into the T1c LDS layout; t1s=0: recompute via t1_tile.
__global__ __launch_bounds__(256) void k_final(const float* __restrict__ ws,
                                               const float* __restrict__ P11,
                                               const float* __restrict__ P40,
                                               const float* __restrict__ P12,
                                               float* __restrict__ out,
                                               long long out_cap, int interleaved,
                                               int t1s){
  __shared__ float sm[9156];   // T1c [0,8514); W2l [8516,9028); s1 [9028); t1 [9092)
  int bid=blockIdx.x, b=bid>>3, pblk=bid&7, tid=threadIdx.x;
  int og=tid&7, pg=tid>>3, lloc=pg>>2, c0=og*8;
  for (int t=tid;t<512;t+=256) sm[8516+t] = 2.0f*P12[t];   // [o2*64+c]
  if (tid<64) sm[9028+tid]=ws[OFF_S1+tid];
  else if (tid<128) sm[9092+(tid-64)]=ws[OFF_T1+(tid-64)];
  if (t1s){
    size_t base = OFF_T1S + ((size_t)b*8 + pblk)*8192;
    for (int t=tid;t<8192;t+=256){
      float v = ws[base+t];
      int j = t>>10, lane=(t&1023)>>2, i=t&3;
      int c = (lane&7)*8 + j;
      int p = (lane>>5)*16 + ((lane>>3)&3)*4 + i;
      sm[c*133 + (c>>3) + p] = v;
    }
    __syncthreads();
  } else {
    float acc[8][4];
    t1_tile(sm, ws, P11, P40, b, pblk, tid, acc, og, pg, lloc, c0);
    __syncthreads();
    {
      int kg = pg&3;
      #pragma unroll
      for (int i=0;i<4;++i){
        int p = lloc*16 + kg*4 + i;
        #pragma unroll
        for (int j=0;j<8;++j) sm[(c0+j)*133 + og + p] = acc[j][i];  // T1c staggered
      }
    }
    __syncthreads();
  }
  if (tid < 128){
    int p = tid, k = p & 15, lglob = pblk*8 + (p>>4);
    float a2[8];
    {
      const float* xp = ws + OFF_X2 + ((size_t)b*64+lglob)*8;
      const float* yp = ws + OFF_Y2 + ((size_t)b*16+k)*8;
      float4 x0_ = *(const float4*)&xp[0];
      float4 x1_ = *(const float4*)&xp[4];
      float4 y0_ = *(const float4*)&yp[0];
      float4 y1_ = *(const float4*)&yp[4];
      a2[0]=x0_.x+y0_.x; a2[1]=x0_.y+y0_.y; a2[2]=x0_.z+y0_.z; a2[3]=x0_.w+y0_.w;
      a2[4]=x1_.x+y1_.x; a2[5]=x1_.y+y1_.y; a2[6]=x1_.z+y1_.z; a2[7]=x1_.w+y1_.w;
    }
    for (int c=0;c<64;++c){
      float tn = sm[9028+c]*sm[c*133 + (c>>3) + p] + sm[9092+c];   // s1*T1+t1
      #pragma unroll
      for (int o2=0;o2<8;++o2) a2[o2] += sm[8516+o2*64+c]*tn;
    }
    float nrm=0.f;
    #pragma unroll
    for (int o2=0;o2<8;++o2) nrm += a2[o2]*a2[o2];
    float inv = 1.0f/sqrtf(nrm);
    size_t pos = (size_t)b*PPP + lglob*KKK + k;
    if (interleaved){
      long long idx = (long long)pos*8;
      if (idx+8 <= out_cap){
        *(float4*)&out[idx]   = make_float4(a2[0]*inv, a2[4]*inv, a2[1]*inv, a2[5]*inv);
        *(float4*)&out[idx+4] = make_float4(a2[2]*inv, a2[6]*inv, a2[3]*inv, a2[7]*inv);
      }
    } else {
      long long idx = (long long)pos*4;
      if (idx+4 <= out_cap)
        *(float4*)&out[idx] = make_float4(a2[0]*inv, a2[1]*inv, a2[2]*inv, a2[3]*inv);
    }
  }
}

extern "C" void kernel_launch(void* const* d_in, const int* in_sizes, int n_in,
                              void* d_out, int out_size, void* d_ws, size_t ws_size,
                              hipStream_t stream) {
  if (n_in < 15) return;
  if (in_sizes[0] != BRR*4096 || in_sizes[1] != BRR*4096) return;
  if (in_sizes[4] != 512)  return;   // P4_0 (64,8)
  if (in_sizes[7] != 4096) return;   // P1_1 (64,64)
  if (in_sizes[12] != 512) return;   // P1_2 (8,64)
  if (ws_size < (size_t)WS_FLOATS*4) return;   // clean fail, not a fault

  const float* Hr   = (const float*)d_in[0];
  const float* Hi   = (const float*)d_in[1];
  const float* P4_0 = (const float*)d_in[4];
  const float* g0   = (const float*)d_in[5];
  const float* b0   = (const float*)d_in[6];
  const float* P1_1 = (const float*)d_in[7];
  const float* P2_1 = (const float*)d_in[8];
  const float* P4_1 = (const float*)d_in[9];
  const float* g1   = (const float*)d_in[10];
  const float* b1   = (const float*)d_in[11];
  const float* P1_2 = (const float*)d_in[12];
  const float* P2_2 = (const float*)d_in[13];
  const float* P4_2 = (const float*)d_in[14];
  float* ws  = (float*)d_ws;
  float* out = (float*)d_out;
  int interleaved = (out_size >= 4194304) ? 1 : 0;
  int big = (ws_size >= (size_t)WS_BIG*4) ? 1 : 0;   // T1-spill path needs ~155 MiB

  k_zero<<<4, 256, 0, stream>>>((float4*)(ws + OFF_SUM0), 4096/4);
  k_prep<<<BRR, 256, 0, stream>>>(Hr, Hi, P4_0, ws);
  k_bn<<<1, 64, 0, stream>>>(ws, g0, b0, OFF_SUM0, OFF_S0);
  k_xy1<<<2560, 256, 0, stream>>>(ws, P2_1, P4_1);
  if (big) k_pass1<<<BRR*2, 256, 0, stream>>>(ws, P1_1, P4_0, 1, 1);
  else     k_pass1<<<BRR,   256, 0, stream>>>(ws, P1_1, P4_0, 0, 0);
  k_bn<<<1, 64, 0, stream>>>(ws, g1, b1, OFF_SUM1, OFF_S1);
  k_xy2s<<<BRR, 256, 0, stream>>>(ws, P2_2, P4_2, big);
  k_final<<<BRR*8, 256, 0, stream>>>(ws, P1_1, P4_0, P1_2, out,
                                     (long long)out_size, interleaved, big);
}